// Round 1
// baseline (834.453 us; speedup 1.0000x reference)
//
#include <hip/hip_runtime.h>

typedef unsigned short u16;
typedef unsigned int u32;
typedef short bf16x8 __attribute__((ext_vector_type(8)));   // 8 bf16 (4 VGPRs)
typedef float f32x4 __attribute__((ext_vector_type(4)));

#define NB   64
#define NC   256
#define NO   256     // conv1 out channels
#define NM   1024    // LF*LF
#define PW   44      // padded width (32 + 2*6)
#define PPIX 1936    // 44*44

__device__ __forceinline__ u16 f2bf(float f) {
    u32 u = __builtin_bit_cast(u32, f);
    u32 r = (u + 0x7FFFu + ((u >> 16) & 1u)) >> 16;   // RNE
    return (u16)r;
}
// async global->LDS, 16B/lane; LDS dest is wave-uniform base + lane*16
__device__ __forceinline__ void ld16(const void* g, void* l) {
    __builtin_amdgcn_global_load_lds((const __attribute__((address_space(1))) u32*)g,
                                     (__attribute__((address_space(3))) u32*)l, 16, 0, 0);
}

// ---------- x[b][c][ij] (f32) -> xp[b][padded pix][c] (bf16), zero border (memset'd) ----------
__global__ __launch_bounds__(256) void k_transpose_pad(const float* __restrict__ x, u16* __restrict__ xp) {
    __shared__ u16 tile[64 * 65];
    const int b = blockIdx.z, ij0 = blockIdx.x * 64, c0 = blockIdx.y * 64;
    const int tid = threadIdx.x;
#pragma unroll
    for (int it = 0; it < 16; ++it) {
        int idx = it * 256 + tid;
        int cr = idx >> 6, ijr = idx & 63;
        tile[ijr * 65 + cr] = f2bf(x[((size_t)(b * NC + c0 + cr) << 10) + ij0 + ijr]);
    }
    __syncthreads();
#pragma unroll
    for (int it = 0; it < 16; ++it) {
        int idx = it * 256 + tid;
        int ijr = idx >> 6, cr = idx & 63;
        int pix = ij0 + ijr;
        int i = pix >> 5, j = pix & 31;
        int prow = (i + 6) * PW + (j + 6);
        xp[((size_t)(b * PPIX + prow) << 8) + c0 + cr] = tile[ijr * 65 + cr];
    }
}

// ---------- conv1_w (O,C,7,7) f32 -> w1t[tap][o][c] bf16 ----------
__global__ __launch_bounds__(256) void k_w1prep(const float* __restrict__ w1, u16* __restrict__ w1t) {
    const int o = blockIdx.x, c = threadIdx.x;
    const float* src = w1 + ((size_t)(o * NC + c)) * 49;
#pragma unroll
    for (int t = 0; t < 49; ++t)
        w1t[((size_t)(t * NO + o) << 8) + c] = f2bf(src[t]);
}

// ---------- conv1: h[b][ij][o] = sum_{tap,c} xp[..][c] * w1t[tap][o][c]; + bn1 stats ----------
// 256(M=pixels) x 256(N=outch) tile, 8 waves (2M x 4N), per-wave 128x64 out.
// BK=32, double-buffered LDS (64 KB), staged 2 K-steps ahead with COUNTED vmcnt(4)
// (never drained to 0 in the main loop), raw s_barriers (T3+T4), setprio around
// MFMA (T5), and XOR chunk-swizzled LDS (T2: pre-swizzled global source since
// global_load_lds writes linearly; read side applies the same involution).
// K-step order: ci2 (32-ch chunk) OUTERMOST, tap inner -> consecutive steps are
// consecutive taps with ~95% overlapping A-windows (L2-resident).
#define C1NS 392   // 8 ci2 * 49 taps

__global__ __launch_bounds__(512, 2) void k_conv1(const u16* __restrict__ xp, const u16* __restrict__ w1t,
                                                  u16* __restrict__ h, float* __restrict__ s1, float* __restrict__ q1) {
    __shared__ u16 lsA[2 * 256 * 32];   // [buf][pix row 256][32 ch]
    __shared__ u16 lsB[2 * 256 * 32];   // [buf][o row 256][32 ch]
    const int tid = threadIdx.x, wv = tid >> 6, lane = tid & 63;
    const int wm = wv & 1, wn = wv >> 1;
    const int bb = blockIdx.z, ij0 = blockIdx.x * 256;

    f32x4 acc[8][4] = {};

    // ---- staging addresses: each wave stages 32 rows of A and of B per K-step (2 ld16 calls each)
    // lane l in a call writes LDS row base+(l>>2), physical 16B-chunk (l&3);
    // source is pre-swizzled: logical chunk = (l&3) ^ ((l>>3)&3)  [= phys ^ ((row>>1)&3)]
    const int lq = lane >> 2;
    const int csrc = (((lane & 3) ^ ((lane >> 3) & 3)) << 3);   // u16 elements
    int asrc[2], bsrc[2], lOff[2];
#pragma unroll
    for (int c = 0; c < 2; ++c) {
        int r = (wv << 5) + (c << 4) + lq;          // tile row 0..255
        int pix = ij0 + r;
        int i = pix >> 5, j = pix & 31;
        asrc[c] = ((bb * PPIX + i * PW + j) << 8) + csrc;
        bsrc[c] = (r << 8) + csrc;
        lOff[c] = ((wv << 5) + (c << 4)) << 5;      // wave-uniform LDS row offset * 32
    }
    // ---- fragment read bases: row stride 64B; swizzled chunk = (lane>>4) ^ ((row>>1)&3)
    const int chsw = ((lane >> 4) ^ (((lane & 15) >> 1) & 3)) << 3;
    const u16* pA0 = lsA + ((((wm << 7) + (lane & 15)) << 5) + chsw);
    const u16* pB0 = lsB + ((((wn << 6) + (lane & 15)) << 5) + chsw);

    // ---- uniform K-step decomposition counters for the staging stream
    int sp = 0, sq = 0, stap = 0, sci = 0;
    auto STAGE = [&](int ks) {
        const int base = (ks & 1) << 13;            // buffer stride 8192 u16
        const int toff = (((sp << 1) * PW + (sq << 1)) << 8) + (sci << 5);
        const int woff = (stap << 16) + (sci << 5);
#pragma unroll
        for (int c = 0; c < 2; ++c) ld16(xp + asrc[c] + toff, (u16*)lsA + base + lOff[c]);
#pragma unroll
        for (int c = 0; c < 2; ++c) ld16(w1t + woff + bsrc[c], (u16*)lsB + base + lOff[c]);
        if (++sq == 7) { sq = 0; ++sp; }
        if (++stap == 49) { stap = 0; sp = 0; sq = 0; ++sci; }
    };
    auto COMPUTE = [&](int k) {
        const int base = (k & 1) << 13;
        const u16* pA = pA0 + base;
        const u16* pB = pB0 + base;
        bf16x8 bv[4];
#pragma unroll
        for (int fj = 0; fj < 4; ++fj) bv[fj] = *(const bf16x8*)(pB + (fj << 9));
        __builtin_amdgcn_s_setprio(1);
#pragma unroll
        for (int fi = 0; fi < 8; ++fi) {
            bf16x8 af = *(const bf16x8*)(pA + (fi << 9));
#pragma unroll
            for (int fj = 0; fj < 4; ++fj)
                acc[fi][fj] = __builtin_amdgcn_mfma_f32_16x16x32_bf16(af, bv[fj], acc[fi][fj], 0, 0, 0);
        }
        __builtin_amdgcn_s_setprio(0);
    };

    // ---- prologue: fill both buffers, wait only the first (counted)
    STAGE(0);
    STAGE(1);
    __builtin_amdgcn_sched_barrier(0);
    asm volatile("s_waitcnt vmcnt(4)" ::: "memory");
    __builtin_amdgcn_s_barrier();
    __builtin_amdgcn_sched_barrier(0);

    // ---- main loop: compute k, then refill its buffer with k+2; wait k+1 (counted vmcnt(4))
#pragma unroll 2
    for (int k = 0; k < C1NS - 2; ++k) {
        COMPUTE(k);
        __builtin_amdgcn_sched_barrier(0);
        __builtin_amdgcn_s_barrier();               // all waves done reading buf[k&1]
        __builtin_amdgcn_sched_barrier(0);
        STAGE(k + 2);                               // overwrite buf[k&1]
        __builtin_amdgcn_sched_barrier(0);
        asm volatile("s_waitcnt vmcnt(4)" ::: "memory");   // k+1's 4 loads done; k+2's stay in flight
        __builtin_amdgcn_s_barrier();               // collectivize
        __builtin_amdgcn_sched_barrier(0);
    }
    // ---- tail: two peeled steps, final drain
    COMPUTE(C1NS - 2);
    __builtin_amdgcn_sched_barrier(0);
    asm volatile("s_waitcnt vmcnt(0)" ::: "memory");
    __builtin_amdgcn_s_barrier();
    __builtin_amdgcn_sched_barrier(0);
    COMPUTE(C1NS - 1);

    // ---- epilogue: store bf16 h + per-column (o) sum/sumsq for bn1
    const int colb = (wn << 6) + (lane & 15);
    const int rowb = ij0 + (wm << 7) + ((lane >> 4) << 2);
#pragma unroll
    for (int fj = 0; fj < 4; ++fj) {
        const int col = colb + (fj << 4);
        float s = 0.f, qq = 0.f;
#pragma unroll
        for (int fi = 0; fi < 8; ++fi) {
            const int row = rowb + (fi << 4);
#pragma unroll
            for (int v = 0; v < 4; ++v) {
                float val = acc[fi][fj][v];
                h[((size_t)((bb << 10) + row + v) << 8) + col] = f2bf(val);
                s += val; qq += val * val;
            }
        }
        s += __shfl_xor(s, 16);  s += __shfl_xor(s, 32);
        qq += __shfl_xor(qq, 16); qq += __shfl_xor(qq, 32);
        if (lane < 16) { atomicAdd(&s1[col], s); atomicAdd(&q1[col], qq); }
    }
}

// ---------- bn1 finalize: only the multiplicative part survives (additive shifts cancel in bn2) ----------
__global__ void k_bn1fin(const float* __restrict__ s1, const float* __restrict__ q1,
                         const float* __restrict__ g1, float* __restrict__ a1) {
    const int o = threadIdx.x;
    float mean = s1[o] * (1.f / 65536.f);
    float var  = fmaxf(q1[o] * (1.f / 65536.f) - mean * mean, 0.f);
    a1[o] = g1[o] * rsqrtf(var + 1e-5f);
}

// ---------- fold bn1 scale into conv2 weights: w2s[m][c] = w2[m][c] * a1[c] (bf16) ----------
__global__ __launch_bounds__(256) void k_fold2(const float* __restrict__ w2, const float* __restrict__ a1,
                                               u16* __restrict__ w2s) {
    const int m = blockIdx.x, c = threadIdx.x;
    size_t idx = ((size_t)m << 8) + c;
    w2s[idx] = f2bf(w2[idx] * a1[c]);
}

// ---------- conv2 (1x1): kb[b][ij][m] = sum_c h[b][ij][c]*w2s[m][c]; + bn2 stats ----------
__global__ __launch_bounds__(256) void k_conv2(const u16* __restrict__ h, const u16* __restrict__ w2s,
                                               u16* __restrict__ kb, float* __restrict__ s2, float* __restrict__ q2) {
    __shared__ u16 lsA[128 * 32];
    __shared__ u16 lsB[128 * 32];
    const int tid = threadIdx.x, wv = tid >> 6, lane = tid & 63;
    const int wm = wv & 1, wn = wv >> 1;
    const int bb = blockIdx.z, ij0 = blockIdx.x * 128, m0 = blockIdx.y * 128;

    f32x4 acc[4][4] = {};
    const int lr = lane >> 2, lc8 = (lane & 3) << 3;
    int arow[2], brw[2];
    u16 *dA[2], *dB[2];
#pragma unroll
    for (int u = 0; u < 2; ++u) {
        int r = (wv << 5) + (u << 4) + lr;
        arow[u] = (((bb << 10) + ij0 + r) << 8) + lc8;
        brw[u]  = ((m0 + r) << 8) + lc8;
        dA[u] = lsA + (((wv << 5) + (u << 4)) << 5);
        dB[u] = lsB + (((wv << 5) + (u << 4)) << 5);
    }
    const u16* pA0 = lsA + (((wm << 6) + (lane & 15)) << 5) + ((lane >> 4) << 3);
    const u16* pB0 = lsB + (((wn << 6) + (lane & 15)) << 5) + ((lane >> 4) << 3);

    for (int s = 0; s < 8; ++s) {
        const int cc = s << 5;
#pragma unroll
        for (int u = 0; u < 2; ++u) {
            ld16(h + arow[u] + cc, dA[u]);
            ld16(w2s + brw[u] + cc, dB[u]);
        }
        __syncthreads();
        bf16x8 af[4], bv[4];
#pragma unroll
        for (int f = 0; f < 4; ++f) af[f] = *(const bf16x8*)(pA0 + (f << 9));
#pragma unroll
        for (int f = 0; f < 4; ++f) bv[f] = *(const bf16x8*)(pB0 + (f << 9));
#pragma unroll
        for (int fi = 0; fi < 4; ++fi)
#pragma unroll
            for (int fj = 0; fj < 4; ++fj)
                acc[fi][fj] = __builtin_amdgcn_mfma_f32_16x16x32_bf16(af[fi], bv[fj], acc[fi][fj], 0, 0, 0);
        __syncthreads();
    }
    const int colb = m0 + (wn << 6) + (lane & 15);
    const int rowb = ij0 + (wm << 6) + ((lane >> 4) << 2);
#pragma unroll
    for (int fj = 0; fj < 4; ++fj) {
        const int col = colb + (fj << 4);
        float s = 0.f, qq = 0.f;
#pragma unroll
        for (int fi = 0; fi < 4; ++fi) {
            const int row = rowb + (fi << 4);
#pragma unroll
            for (int v = 0; v < 4; ++v) {
                float val = acc[fi][fj][v];
                kb[((size_t)((bb << 10) + row + v) << 10) + col] = f2bf(val);
                s += val; qq += val * val;
            }
        }
        s += __shfl_xor(s, 16);  s += __shfl_xor(s, 32);
        qq += __shfl_xor(qq, 16); qq += __shfl_xor(qq, 32);
        if (lane < 16) { atomicAdd(&s2[col], s); atomicAdd(&q2[col], qq); }
    }
}

__global__ void k_bn2fin(const float* __restrict__ s2, const float* __restrict__ q2,
                         const float* __restrict__ g2, const float* __restrict__ b2,
                         float* __restrict__ a2, float* __restrict__ b2f) {
    const int m = blockIdx.x * 256 + threadIdx.x;
    float mean = s2[m] * (1.f / 65536.f);
    float var  = fmaxf(q2[m] * (1.f / 65536.f) - mean * mean, 0.f);
    float a = g2[m] * rsqrtf(var + 1e-5f);
    a2[m] = a;
    b2f[m] = b2[m] - mean * a;
}

// ---------- softmax over m (1024) per (b,ij) row, bn2 affine applied, in place ----------
__global__ __launch_bounds__(256) void k_softmax(u16* __restrict__ kb,
                                                 const float* __restrict__ a2, const float* __restrict__ b2f) {
    __shared__ float redm[4], reds[4];
    const int row = (blockIdx.y << 10) + blockIdx.x;
    u16* base = kb + ((size_t)row << 10);
    const int tid = threadIdx.x, lane = tid & 63, wv = tid >> 6;
    const int m0 = tid << 2;
    uint2 rw = *(const uint2*)(base + m0);
    float u[4];
    u[0] = __builtin_bit_cast(float, (rw.x & 0xFFFFu) << 16);
    u[1] = __builtin_bit_cast(float, rw.x & 0xFFFF0000u);
    u[2] = __builtin_bit_cast(float, (rw.y & 0xFFFFu) << 16);
    u[3] = __builtin_bit_cast(float, rw.y & 0xFFFF0000u);
#pragma unroll
    for (int i = 0; i < 4; ++i) u[i] = a2[m0 + i] * u[i] + b2f[m0 + i];
    float mx = fmaxf(fmaxf(u[0], u[1]), fmaxf(u[2], u[3]));
#pragma unroll
    for (int off = 32; off; off >>= 1) mx = fmaxf(mx, __shfl_xor(mx, off));
    if (lane == 0) redm[wv] = mx;
    __syncthreads();
    mx = fmaxf(fmaxf(redm[0], redm[1]), fmaxf(redm[2], redm[3]));
    float e[4], s = 0.f;
#pragma unroll
    for (int i = 0; i < 4; ++i) { e[i] = __expf(u[i] - mx); s += e[i]; }
#pragma unroll
    for (int off = 32; off; off >>= 1) s += __shfl_xor(s, off);
    if (lane == 0) reds[wv] = s;
    __syncthreads();
    float inv = 1.f / (reds[0] + reds[1] + reds[2] + reds[3]);
    u32 o0 = (u32)f2bf(e[0] * inv) | ((u32)f2bf(e[1] * inv) << 16);
    u32 o1 = (u32)f2bf(e[2] * inv) | ((u32)f2bf(e[3] * inv) << 16);
    *(uint2*)(base + m0) = make_uint2(o0, o1);
}

// ---------- final: out[b][ij][c] = sum_m ksm[b][ij][m] * x[b][c][m]; x is f32, out f32 ----------
__global__ __launch_bounds__(256) void k_final(const u16* __restrict__ ksm, const float* __restrict__ x,
                                               float* __restrict__ out) {
    __shared__ u16 lsA[128 * 32];
    __shared__ u16 lsB[128 * 32];
    const int tid = threadIdx.x, wv = tid >> 6, lane = tid & 63;
    const int wm = wv & 1, wn = wv >> 1;
    const int bb = blockIdx.z, ij0 = blockIdx.x * 128, c0 = blockIdx.y * 128;

    f32x4 acc[4][4] = {};
    const int lr = lane >> 2, lc8 = (lane & 3) << 3;
    int arow[2], brw[2];
    u16 *dA[2], *sB[2];
#pragma unroll
    for (int u = 0; u < 2; ++u) {
        int r = (wv << 5) + (u << 4) + lr;
        arow[u] = (((bb << 10) + ij0 + r) << 10) + lc8;
        brw[u]  = (((bb << 8) + c0 + r) << 10) + lc8;    // element offset into f32 x
        dA[u] = lsA + (((wv << 5) + (u << 4)) << 5);     // wave-uniform, glld
        sB[u] = lsB + (((wv << 5) + (u << 4) + lr) << 5) + lc8;  // per-lane store slot
    }
    const u16* pA0 = lsA + (((wm << 6) + (lane & 15)) << 5) + ((lane >> 4) << 3);
    const u16* pB0 = lsB + (((wn << 6) + (lane & 15)) << 5) + ((lane >> 4) << 3);

    for (int s = 0; s < 32; ++s) {
        const int cc = s << 5;
#pragma unroll
        for (int u = 0; u < 2; ++u) ld16(ksm + arow[u] + cc, dA[u]);
        float4 f00 = *(const float4*)(x + brw[0] + cc);
        float4 f01 = *(const float4*)(x + brw[0] + cc + 4);
        float4 f10 = *(const float4*)(x + brw[1] + cc);
        float4 f11 = *(const float4*)(x + brw[1] + cc + 4);
        uint4 vb0, vb1;
        vb0.x = (u32)f2bf(f00.x) | ((u32)f2bf(f00.y) << 16);
        vb0.y = (u32)f2bf(f00.z) | ((u32)f2bf(f00.w) << 16);
        vb0.z = (u32)f2bf(f01.x) | ((u32)f2bf(f01.y) << 16);
        vb0.w = (u32)f2bf(f01.z) | ((u32)f2bf(f01.w) << 16);
        vb1.x = (u32)f2bf(f10.x) | ((u32)f2bf(f10.y) << 16);
        vb1.y = (u32)f2bf(f10.z) | ((u32)f2bf(f10.w) << 16);
        vb1.z = (u32)f2bf(f11.x) | ((u32)f2bf(f11.y) << 16);
        vb1.w = (u32)f2bf(f11.z) | ((u32)f2bf(f11.w) << 16);
        *(uint4*)sB[0] = vb0;
        *(uint4*)sB[1] = vb1;
        __syncthreads();
        bf16x8 af[4], bv[4];
#pragma unroll
        for (int f = 0; f < 4; ++f) af[f] = *(const bf16x8*)(pA0 + (f << 9));
#pragma unroll
        for (int f = 0; f < 4; ++f) bv[f] = *(const bf16x8*)(pB0 + (f << 9));
#pragma unroll
        for (int fi = 0; fi < 4; ++fi)
#pragma unroll
            for (int fj = 0; fj < 4; ++fj)
                acc[fi][fj] = __builtin_amdgcn_mfma_f32_16x16x32_bf16(af[fi], bv[fj], acc[fi][fj], 0, 0, 0);
        __syncthreads();
    }
    const int colb = c0 + (wn << 6) + (lane & 15);
    const int rowb = ij0 + (wm << 6) + ((lane >> 4) << 2);
#pragma unroll
    for (int fi = 0; fi < 4; ++fi) {
        const int row = rowb + (fi << 4);
#pragma unroll
        for (int fj = 0; fj < 4; ++fj) {
            const int col = colb + (fj << 4);
#pragma unroll
            for (int v = 0; v < 4; ++v)
                out[((size_t)((bb << 10) + row + v) << 8) + col] = acc[fi][fj][v];
        }
    }
}

extern "C" void kernel_launch(void* const* d_in, const int* in_sizes, int n_in,
                              void* d_out, int out_size, void* d_ws, size_t ws_size,
                              hipStream_t stream) {
    const float* x  = (const float*)d_in[0];
    const float* w1 = (const float*)d_in[1];
    // d_in[2] = conv1_b : cancels through bn1
    const float* g1 = (const float*)d_in[3];
    // d_in[4] = bn1_b : cancels through bn2 (additive per-c constant -> per-m constant)
    const float* w2 = (const float*)d_in[5];
    // d_in[6] = conv2_b : cancels through bn2
    const float* g2 = (const float*)d_in[7];
    const float* b2 = (const float*)d_in[8];
    float* out = (float*)d_out;
    char* ws = (char*)d_ws;

    // ws layout (~174.3 MB): region0 shared by xp (63.4MB, dead after conv1) and kb (134MB)
    u16* xp  = (u16*)ws;
    u16* kb  = (u16*)ws;
    u16* h   = (u16*)(ws + 134217728);                 // 33.5 MB
    u16* w1t = (u16*)(ws + 134217728 + 33554432);      // 6.4 MB, shared with w2s (dead after conv1)
    u16* w2s = w1t;
    char* sm = ws + 134217728 + 33554432 + 6422528;
    float* s1  = (float*)(sm);
    float* q1  = (float*)(sm + 1024);
    float* s2  = (float*)(sm + 2048);
    float* q2  = (float*)(sm + 6144);
    float* a1  = (float*)(sm + 10240);
    float* a2  = (float*)(sm + 14336);
    float* b2f = (float*)(sm + 18432);

    hipMemsetAsync(sm, 0, 10240, stream);                             // stats accumulators
    hipMemsetAsync(xp, 0, (size_t)NB * PPIX * 256 * 2, stream);       // padded-input zeros
    k_transpose_pad<<<dim3(16, 4, NB), 256, 0, stream>>>(x, xp);
    k_w1prep<<<dim3(256), 256, 0, stream>>>(w1, w1t);
    k_conv1<<<dim3(4, 1, NB), 512, 0, stream>>>(xp, w1t, h, s1, q1);
    k_bn1fin<<<dim3(1), 256, 0, stream>>>(s1, q1, g1, a1);
    k_fold2<<<dim3(1024), 256, 0, stream>>>(w2, a1, w2s);
    k_conv2<<<dim3(8, 8, NB), 256, 0, stream>>>(h, w2s, kb, s2, q2);
    k_bn2fin<<<dim3(4), 256, 0, stream>>>(s2, q2, g2, b2, a2, b2f);
    k_softmax<<<dim3(1024, NB), 256, 0, stream>>>(kb, a2, b2f);
    k_final<<<dim3(8, 2, NB), 256, 0, stream>>>(kb, x, out);
}

// Round 2
// 805.738 us; speedup vs baseline: 1.0356x; 1.0356x over previous
//
#include <hip/hip_runtime.h>

typedef unsigned short u16;
typedef unsigned int u32;
typedef short bf16x8 __attribute__((ext_vector_type(8)));   // 8 bf16 (4 VGPRs)
typedef float f32x4 __attribute__((ext_vector_type(4)));

#define NB   64
#define NC   256
#define NO   256     // conv1 out channels
#define NM   1024    // LF*LF
#define PW   44      // padded width (32 + 2*6)
#define PPIX 1936    // 44*44

__device__ __forceinline__ u16 f2bf(float f) {
    u32 u = __builtin_bit_cast(u32, f);
    u32 r = (u + 0x7FFFu + ((u >> 16) & 1u)) >> 16;   // RNE
    return (u16)r;
}
// async global->LDS, 16B/lane; LDS dest is wave-uniform base + lane*16
__device__ __forceinline__ void ld16(const void* g, void* l) {
    __builtin_amdgcn_global_load_lds((const __attribute__((address_space(1))) u32*)g,
                                     (__attribute__((address_space(3))) u32*)l, 16, 0, 0);
}

// ---------- x[b][c][ij] (f32) -> xp[b][padded pix][c] (bf16), zero border (memset'd) ----------
__global__ __launch_bounds__(256) void k_transpose_pad(const float* __restrict__ x, u16* __restrict__ xp) {
    __shared__ u16 tile[64 * 65];
    const int b = blockIdx.z, ij0 = blockIdx.x * 64, c0 = blockIdx.y * 64;
    const int tid = threadIdx.x;
#pragma unroll
    for (int it = 0; it < 16; ++it) {
        int idx = it * 256 + tid;
        int cr = idx >> 6, ijr = idx & 63;
        tile[ijr * 65 + cr] = f2bf(x[((size_t)(b * NC + c0 + cr) << 10) + ij0 + ijr]);
    }
    __syncthreads();
#pragma unroll
    for (int it = 0; it < 16; ++it) {
        int idx = it * 256 + tid;
        int ijr = idx >> 6, cr = idx & 63;
        int pix = ij0 + ijr;
        int i = pix >> 5, j = pix & 31;
        int prow = (i + 6) * PW + (j + 6);
        xp[((size_t)(b * PPIX + prow) << 8) + c0 + cr] = tile[ijr * 65 + cr];
    }
}

// ---------- conv1_w (O,C,7,7) f32 -> w1t[tap][o][c] bf16 ----------
__global__ __launch_bounds__(256) void k_w1prep(const float* __restrict__ w1, u16* __restrict__ w1t) {
    const int o = blockIdx.x, c = threadIdx.x;
    const float* src = w1 + ((size_t)(o * NC + c)) * 49;
#pragma unroll
    for (int t = 0; t < 49; ++t)
        w1t[((size_t)(t * NO + o) << 8) + c] = f2bf(src[t]);
}

// ---------- conv1: 8-phase deep-pipelined 256x256 MFMA GEMM ----------
// h[b][ij][o] = sum_{tap,c} xp[..][c] * w1t[tap][o][c]; + bn1 stats.
// K = 196 tiles of BK=64 (tap-inner, ci outer for L2 locality of A windows).
// LDS 128 KiB: lsA/lsB = [2 buf][2 kh][256 rows][32 u16] (kh = K-half of 32).
// Per iteration (2 K-tiles, 8 phases): each phase stages ONE half-tile
// (2 ld16/thread), ds_reads its fragments (A cached across phase pairs),
// 16 MFMA under setprio, barrier. vmcnt(8) at even phases only -> 4
// half-tiles permanently in flight; never drained in the main loop.
// Stage slot legality (verified): each (buf,kh,A/B) region is overwritten
// >=1 barrier after its last reader and vmcnt-verified >=2 phases before
// its next reader.
// LDS swizzle: physical 16B-chunk = logical ^ ((row>>1)&3); applied via
// pre-swizzled GLOBAL source (glld dest stays linear, rule 21) and the
// same involution on the ds_read address -> 2-way (free) bank pattern.
__global__ __launch_bounds__(512, 2) void k_conv1(const u16* __restrict__ xp, const u16* __restrict__ w1t,
                                                  u16* __restrict__ h, float* __restrict__ s1, float* __restrict__ q1) {
    __shared__ u16 lsA[2 * 2 * 256 * 32];   // 64 KB
    __shared__ u16 lsB[2 * 2 * 256 * 32];   // 64 KB
    const int tid = threadIdx.x, wv = tid >> 6, lane = tid & 63;
    const int wm = wv & 1, wn = wv >> 1;
    const int bb = blockIdx.z, ij0 = blockIdx.x * 256;

    f32x4 acc[8][4] = {};
    bf16x8 afr[8];

    // ---- staging geometry: call c covers rows c*128 + (tid>>2), chunk tid&3 (16B)
    // pre-swizzled source chunk: lc = (tid&3) ^ ((tid>>3)&3)
    const int lc8 = (((tid & 3) ^ ((tid >> 3) & 3)) << 3);   // u16 elements
    int aRow[2], bRow[2], dstO[2];
#pragma unroll
    for (int c = 0; c < 2; ++c) {
        int r = (c << 7) + (tid >> 2);
        int pix = ij0 + r, i = pix >> 5, j = pix & 31;
        aRow[c] = ((bb * PPIX + i * PW + j) << 8) + lc8;
        bRow[c] = (r << 8) + lc8;
        dstO[c] = ((c << 7) + (wv << 4)) << 5;      // wave-uniform LDS u16 offset
    }
    // ---- fragment read bases: phys chunk = (lane>>4) ^ (((lane&15)>>1)&3)
    const int chsw = (((lane >> 4) ^ (((lane & 15) >> 1) & 3)) << 3);
    const u16* pA0 = lsA + (((wm << 7) + (lane & 15)) << 5) + chsw;
    const u16* pB0 = lsB + (((wn << 6) + (lane & 15)) << 5) + chsw;

    // ---- sequential half-tile stage stream: per tile {A kh0, B kh0, A kh1, B kh1}
    int sci = 0, stap = 0, sp = 0, sq = 0, sbuf = 0;
    auto SA = [&](int kh) {
        const int toff = (((sp << 1) * PW + (sq << 1)) << 8) + (sci << 6) + (kh << 5);
        u16* dst = (u16*)lsA + (sbuf << 14) + (kh << 13);
#pragma unroll
        for (int c = 0; c < 2; ++c) ld16(xp + aRow[c] + toff, dst + dstO[c]);
    };
    auto SB = [&](int kh) {
        const int woff = (stap << 16) + (sci << 6) + (kh << 5);
        u16* dst = (u16*)lsB + (sbuf << 14) + (kh << 13);
#pragma unroll
        for (int c = 0; c < 2; ++c) ld16(w1t + bRow[c] + woff, dst + dstO[c]);
    };
    auto ADV = [&]() {
        ++stap; ++sq;
        if (sq == 7) { sq = 0; ++sp; }
        if (stap == 49) { stap = 0; sp = 0; sq = 0; ++sci; }
        sbuf ^= 1;
    };
    // ---- compute phases: PHA reloads 8 A-frags + 2 B; PHB reuses A, 2 new B
    auto PHA = [&](int buf, int kh, int fjb) {
        const u16* pB = pB0 + (buf << 14) + (kh << 13);
        bf16x8 b0 = *(const bf16x8*)(pB + (fjb << 9));
        bf16x8 b1 = *(const bf16x8*)(pB + ((fjb + 1) << 9));
        const u16* pA = pA0 + (buf << 14) + (kh << 13);
#pragma unroll
        for (int fi = 0; fi < 8; ++fi) afr[fi] = *(const bf16x8*)(pA + (fi << 9));
        __builtin_amdgcn_s_setprio(1);
#pragma unroll
        for (int fi = 0; fi < 8; ++fi) {
            acc[fi][fjb]     = __builtin_amdgcn_mfma_f32_16x16x32_bf16(afr[fi], b0, acc[fi][fjb], 0, 0, 0);
            acc[fi][fjb + 1] = __builtin_amdgcn_mfma_f32_16x16x32_bf16(afr[fi], b1, acc[fi][fjb + 1], 0, 0, 0);
        }
        __builtin_amdgcn_s_setprio(0);
    };
    auto PHB = [&](int buf, int kh, int fjb) {
        const u16* pB = pB0 + (buf << 14) + (kh << 13);
        bf16x8 b0 = *(const bf16x8*)(pB + (fjb << 9));
        bf16x8 b1 = *(const bf16x8*)(pB + ((fjb + 1) << 9));
        __builtin_amdgcn_s_setprio(1);
#pragma unroll
        for (int fi = 0; fi < 8; ++fi) {
            acc[fi][fjb]     = __builtin_amdgcn_mfma_f32_16x16x32_bf16(afr[fi], b0, acc[fi][fjb], 0, 0, 0);
            acc[fi][fjb + 1] = __builtin_amdgcn_mfma_f32_16x16x32_bf16(afr[fi], b1, acc[fi][fjb + 1], 0, 0, 0);
        }
        __builtin_amdgcn_s_setprio(0);
    };
    auto BAR = [&]() {
        asm volatile("" ::: "memory");
        __builtin_amdgcn_s_barrier();
        asm volatile("" ::: "memory");
    };

    // ---- prologue: tile0 complete + tile1 kh0; allow tile1-kh0's 4 loads in flight
    SA(0); SB(0); SA(1); SB(1); ADV();   // tile 0
    SA(0); SB(0);                        // tile 1, kh0
    asm volatile("s_waitcnt vmcnt(4)" ::: "memory");
    BAR();

    // ---- main loop: tiles 2i (buf0) and 2i+1 (buf1); tiles 0..193
#pragma unroll 1
    for (int i = 0; i < 97; ++i) {
        SA(1); PHA(0, 0, 0); BAR();                                   // P1: stage A(2i+1,kh1)
        SB(1); PHB(0, 0, 2); ADV();
        asm volatile("s_waitcnt vmcnt(8)" ::: "memory"); BAR();       // P2: stage B(2i+1,kh1)
        SA(0); PHA(0, 1, 0); BAR();                                   // P3: stage A(2i+2,kh0)
        SB(0); PHB(0, 1, 2);
        asm volatile("s_waitcnt vmcnt(8)" ::: "memory"); BAR();       // P4: stage B(2i+2,kh0)
        SA(1); PHA(1, 0, 0); BAR();                                   // P5: stage A(2i+2,kh1)
        SB(1); PHB(1, 0, 2); ADV();
        asm volatile("s_waitcnt vmcnt(8)" ::: "memory"); BAR();       // P6: stage B(2i+2,kh1)
        SA(0); PHA(1, 1, 0); BAR();                                   // P7: stage A(2i+3,kh0)
        SB(0); PHB(1, 1, 2);
        asm volatile("s_waitcnt vmcnt(8)" ::: "memory"); BAR();       // P8: stage B(2i+3,kh0)
    }
    // ---- tail: finish staging tile 195 kh1, drain, compute tiles 194/195
    SA(1); SB(1);
    asm volatile("s_waitcnt vmcnt(0)" ::: "memory");
    BAR();
    PHA(0, 0, 0); PHB(0, 0, 2); PHA(0, 1, 0); PHB(0, 1, 2);   // tile 194
    PHA(1, 0, 0); PHB(1, 0, 2); PHA(1, 1, 0); PHB(1, 1, 2);   // tile 195

    // ---- epilogue: store bf16 h + per-column (o) sum/sumsq for bn1
    const int colb = (wn << 6) + (lane & 15);
    const int rowb = ij0 + (wm << 7) + ((lane >> 4) << 2);
#pragma unroll
    for (int fj = 0; fj < 4; ++fj) {
        const int col = colb + (fj << 4);
        float s = 0.f, qq = 0.f;
#pragma unroll
        for (int fi = 0; fi < 8; ++fi) {
            const int row = rowb + (fi << 4);
#pragma unroll
            for (int v = 0; v < 4; ++v) {
                float val = acc[fi][fj][v];
                h[((size_t)((bb << 10) + row + v) << 8) + col] = f2bf(val);
                s += val; qq += val * val;
            }
        }
        s += __shfl_xor(s, 16);  s += __shfl_xor(s, 32);
        qq += __shfl_xor(qq, 16); qq += __shfl_xor(qq, 32);
        if (lane < 16) { atomicAdd(&s1[col], s); atomicAdd(&q1[col], qq); }
    }
}

// ---------- bn1 finalize: only the multiplicative part survives (additive shifts cancel in bn2) ----------
__global__ void k_bn1fin(const float* __restrict__ s1, const float* __restrict__ q1,
                         const float* __restrict__ g1, float* __restrict__ a1) {
    const int o = threadIdx.x;
    float mean = s1[o] * (1.f / 65536.f);
    float var  = fmaxf(q1[o] * (1.f / 65536.f) - mean * mean, 0.f);
    a1[o] = g1[o] * rsqrtf(var + 1e-5f);
}

// ---------- fold bn1 scale into conv2 weights: w2s[m][c] = w2[m][c] * a1[c] (bf16) ----------
__global__ __launch_bounds__(256) void k_fold2(const float* __restrict__ w2, const float* __restrict__ a1,
                                               u16* __restrict__ w2s) {
    const int m = blockIdx.x, c = threadIdx.x;
    size_t idx = ((size_t)m << 8) + c;
    w2s[idx] = f2bf(w2[idx] * a1[c]);
}

// ---------- conv2 (1x1): kb[b][ij][m] = sum_c h[b][ij][c]*w2s[m][c]; + bn2 stats ----------
__global__ __launch_bounds__(256) void k_conv2(const u16* __restrict__ h, const u16* __restrict__ w2s,
                                               u16* __restrict__ kb, float* __restrict__ s2, float* __restrict__ q2) {
    __shared__ u16 lsA[128 * 32];
    __shared__ u16 lsB[128 * 32];
    const int tid = threadIdx.x, wv = tid >> 6, lane = tid & 63;
    const int wm = wv & 1, wn = wv >> 1;
    const int bb = blockIdx.z, ij0 = blockIdx.x * 128, m0 = blockIdx.y * 128;

    f32x4 acc[4][4] = {};
    const int lr = lane >> 2, lc8 = (lane & 3) << 3;
    int arow[2], brw[2];
    u16 *dA[2], *dB[2];
#pragma unroll
    for (int u = 0; u < 2; ++u) {
        int r = (wv << 5) + (u << 4) + lr;
        arow[u] = (((bb << 10) + ij0 + r) << 8) + lc8;
        brw[u]  = ((m0 + r) << 8) + lc8;
        dA[u] = lsA + (((wv << 5) + (u << 4)) << 5);
        dB[u] = lsB + (((wv << 5) + (u << 4)) << 5);
    }
    const u16* pA0 = lsA + (((wm << 6) + (lane & 15)) << 5) + ((lane >> 4) << 3);
    const u16* pB0 = lsB + (((wn << 6) + (lane & 15)) << 5) + ((lane >> 4) << 3);

    for (int s = 0; s < 8; ++s) {
        const int cc = s << 5;
#pragma unroll
        for (int u = 0; u < 2; ++u) {
            ld16(h + arow[u] + cc, dA[u]);
            ld16(w2s + brw[u] + cc, dB[u]);
        }
        __syncthreads();
        bf16x8 af[4], bv[4];
#pragma unroll
        for (int f = 0; f < 4; ++f) af[f] = *(const bf16x8*)(pA0 + (f << 9));
#pragma unroll
        for (int f = 0; f < 4; ++f) bv[f] = *(const bf16x8*)(pB0 + (f << 9));
#pragma unroll
        for (int fi = 0; fi < 4; ++fi)
#pragma unroll
            for (int fj = 0; fj < 4; ++fj)
                acc[fi][fj] = __builtin_amdgcn_mfma_f32_16x16x32_bf16(af[fi], bv[fj], acc[fi][fj], 0, 0, 0);
        __syncthreads();
    }
    const int colb = m0 + (wn << 6) + (lane & 15);
    const int rowb = ij0 + (wm << 6) + ((lane >> 4) << 2);
#pragma unroll
    for (int fj = 0; fj < 4; ++fj) {
        const int col = colb + (fj << 4);
        float s = 0.f, qq = 0.f;
#pragma unroll
        for (int fi = 0; fi < 4; ++fi) {
            const int row = rowb + (fi << 4);
#pragma unroll
            for (int v = 0; v < 4; ++v) {
                float val = acc[fi][fj][v];
                kb[((size_t)((bb << 10) + row + v) << 10) + col] = f2bf(val);
                s += val; qq += val * val;
            }
        }
        s += __shfl_xor(s, 16);  s += __shfl_xor(s, 32);
        qq += __shfl_xor(qq, 16); qq += __shfl_xor(qq, 32);
        if (lane < 16) { atomicAdd(&s2[col], s); atomicAdd(&q2[col], qq); }
    }
}

__global__ void k_bn2fin(const float* __restrict__ s2, const float* __restrict__ q2,
                         const float* __restrict__ g2, const float* __restrict__ b2,
                         float* __restrict__ a2, float* __restrict__ b2f) {
    const int m = blockIdx.x * 256 + threadIdx.x;
    float mean = s2[m] * (1.f / 65536.f);
    float var  = fmaxf(q2[m] * (1.f / 65536.f) - mean * mean, 0.f);
    float a = g2[m] * rsqrtf(var + 1e-5f);
    a2[m] = a;
    b2f[m] = b2[m] - mean * a;
}

// ---------- softmax over m (1024) per (b,ij) row, bn2 affine applied, in place ----------
__global__ __launch_bounds__(256) void k_softmax(u16* __restrict__ kb,
                                                 const float* __restrict__ a2, const float* __restrict__ b2f) {
    __shared__ float redm[4], reds[4];
    const int row = (blockIdx.y << 10) + blockIdx.x;
    u16* base = kb + ((size_t)row << 10);
    const int tid = threadIdx.x, lane = tid & 63, wv = tid >> 6;
    const int m0 = tid << 2;
    uint2 rw = *(const uint2*)(base + m0);
    float u[4];
    u[0] = __builtin_bit_cast(float, (rw.x & 0xFFFFu) << 16);
    u[1] = __builtin_bit_cast(float, rw.x & 0xFFFF0000u);
    u[2] = __builtin_bit_cast(float, (rw.y & 0xFFFFu) << 16);
    u[3] = __builtin_bit_cast(float, rw.y & 0xFFFF0000u);
#pragma unroll
    for (int i = 0; i < 4; ++i) u[i] = a2[m0 + i] * u[i] + b2f[m0 + i];
    float mx = fmaxf(fmaxf(u[0], u[1]), fmaxf(u[2], u[3]));
#pragma unroll
    for (int off = 32; off; off >>= 1) mx = fmaxf(mx, __shfl_xor(mx, off));
    if (lane == 0) redm[wv] = mx;
    __syncthreads();
    mx = fmaxf(fmaxf(redm[0], redm[1]), fmaxf(redm[2], redm[3]));
    float e[4], s = 0.f;
#pragma unroll
    for (int i = 0; i < 4; ++i) { e[i] = __expf(u[i] - mx); s += e[i]; }
#pragma unroll
    for (int off = 32; off; off >>= 1) s += __shfl_xor(s, off);
    if (lane == 0) reds[wv] = s;
    __syncthreads();
    float inv = 1.f / (reds[0] + reds[1] + reds[2] + reds[3]);
    u32 o0 = (u32)f2bf(e[0] * inv) | ((u32)f2bf(e[1] * inv) << 16);
    u32 o1 = (u32)f2bf(e[2] * inv) | ((u32)f2bf(e[3] * inv) << 16);
    *(uint2*)(base + m0) = make_uint2(o0, o1);
}

// ---------- final: out[b][ij][c] = sum_m ksm[b][ij][m] * x[b][c][m]; x is f32, out f32 ----------
__global__ __launch_bounds__(256) void k_final(const u16* __restrict__ ksm, const float* __restrict__ x,
                                               float* __restrict__ out) {
    __shared__ u16 lsA[128 * 32];
    __shared__ u16 lsB[128 * 32];
    const int tid = threadIdx.x, wv = tid >> 6, lane = tid & 63;
    const int wm = wv & 1, wn = wv >> 1;
    const int bb = blockIdx.z, ij0 = blockIdx.x * 128, c0 = blockIdx.y * 128;

    f32x4 acc[4][4] = {};
    const int lr = lane >> 2, lc8 = (lane & 3) << 3;
    int arow[2], brw[2];
    u16 *dA[2], *sB[2];
#pragma unroll
    for (int u = 0; u < 2; ++u) {
        int r = (wv << 5) + (u << 4) + lr;
        arow[u] = (((bb << 10) + ij0 + r) << 10) + lc8;
        brw[u]  = (((bb << 8) + c0 + r) << 10) + lc8;    // element offset into f32 x
        dA[u] = lsA + (((wv << 5) + (u << 4)) << 5);     // wave-uniform, glld
        sB[u] = lsB + (((wv << 5) + (u << 4) + lr) << 5) + lc8;  // per-lane store slot
    }
    const u16* pA0 = lsA + (((wm << 6) + (lane & 15)) << 5) + ((lane >> 4) << 3);
    const u16* pB0 = lsB + (((wn << 6) + (lane & 15)) << 5) + ((lane >> 4) << 3);

    for (int s = 0; s < 32; ++s) {
        const int cc = s << 5;
#pragma unroll
        for (int u = 0; u < 2; ++u) ld16(ksm + arow[u] + cc, dA[u]);
        float4 f00 = *(const float4*)(x + brw[0] + cc);
        float4 f01 = *(const float4*)(x + brw[0] + cc + 4);
        float4 f10 = *(const float4*)(x + brw[1] + cc);
        float4 f11 = *(const float4*)(x + brw[1] + cc + 4);
        uint4 vb0, vb1;
        vb0.x = (u32)f2bf(f00.x) | ((u32)f2bf(f00.y) << 16);
        vb0.y = (u32)f2bf(f00.z) | ((u32)f2bf(f00.w) << 16);
        vb0.z = (u32)f2bf(f01.x) | ((u32)f2bf(f01.y) << 16);
        vb0.w = (u32)f2bf(f01.z) | ((u32)f2bf(f01.w) << 16);
        vb1.x = (u32)f2bf(f10.x) | ((u32)f2bf(f10.y) << 16);
        vb1.y = (u32)f2bf(f10.z) | ((u32)f2bf(f10.w) << 16);
        vb1.z = (u32)f2bf(f11.x) | ((u32)f2bf(f11.y) << 16);
        vb1.w = (u32)f2bf(f11.z) | ((u32)f2bf(f11.w) << 16);
        *(uint4*)sB[0] = vb0;
        *(uint4*)sB[1] = vb1;
        __syncthreads();
        bf16x8 af[4], bv[4];
#pragma unroll
        for (int f = 0; f < 4; ++f) af[f] = *(const bf16x8*)(pA0 + (f << 9));
#pragma unroll
        for (int f = 0; f < 4; ++f) bv[f] = *(const bf16x8*)(pB0 + (f << 9));
#pragma unroll
        for (int fi = 0; fi < 4; ++fi)
#pragma unroll
            for (int fj = 0; fj < 4; ++fj)
                acc[fi][fj] = __builtin_amdgcn_mfma_f32_16x16x32_bf16(af[fi], bv[fj], acc[fi][fj], 0, 0, 0);
        __syncthreads();
    }
    const int colb = c0 + (wn << 6) + (lane & 15);
    const int rowb = ij0 + (wm << 6) + ((lane >> 4) << 2);
#pragma unroll
    for (int fi = 0; fi < 4; ++fi) {
        const int row = rowb + (fi << 4);
#pragma unroll
        for (int fj = 0; fj < 4; ++fj) {
            const int col = colb + (fj << 4);
#pragma unroll
            for (int v = 0; v < 4; ++v)
                out[((size_t)((bb << 10) + row + v) << 8) + col] = acc[fi][fj][v];
        }
    }
}

extern "C" void kernel_launch(void* const* d_in, const int* in_sizes, int n_in,
                              void* d_out, int out_size, void* d_ws, size_t ws_size,
                              hipStream_t stream) {
    const float* x  = (const float*)d_in[0];
    const float* w1 = (const float*)d_in[1];
    // d_in[2] = conv1_b : cancels through bn1
    const float* g1 = (const float*)d_in[3];
    // d_in[4] = bn1_b : cancels through bn2 (additive per-c constant -> per-m constant)
    const float* w2 = (const float*)d_in[5];
    // d_in[6] = conv2_b : cancels through bn2
    const float* g2 = (const float*)d_in[7];
    const float* b2 = (const float*)d_in[8];
    float* out = (float*)d_out;
    char* ws = (char*)d_ws;

    // ws layout (~174.3 MB): region0 shared by xp (63.4MB, dead after conv1) and kb (134MB)
    u16* xp  = (u16*)ws;
    u16* kb  = (u16*)ws;
    u16* h   = (u16*)(ws + 134217728);                 // 33.5 MB
    u16* w1t = (u16*)(ws + 134217728 + 33554432);      // 6.4 MB, shared with w2s (dead after conv1)
    u16* w2s = w1t;
    char* sm = ws + 134217728 + 33554432 + 6422528;
    float* s1  = (float*)(sm);
    float* q1  = (float*)(sm + 1024);
    float* s2  = (float*)(sm + 2048);
    float* q2  = (float*)(sm + 6144);
    float* a1  = (float*)(sm + 10240);
    float* a2  = (float*)(sm + 14336);
    float* b2f = (float*)(sm + 18432);

    hipMemsetAsync(sm, 0, 10240, stream);                             // stats accumulators
    hipMemsetAsync(xp, 0, (size_t)NB * PPIX * 256 * 2, stream);       // padded-input zeros
    k_transpose_pad<<<dim3(16, 4, NB), 256, 0, stream>>>(x, xp);
    k_w1prep<<<dim3(256), 256, 0, stream>>>(w1, w1t);
    k_conv1<<<dim3(4, 1, NB), 512, 0, stream>>>(xp, w1t, h, s1, q1);
    k_bn1fin<<<dim3(1), 256, 0, stream>>>(s1, q1, g1, a1);
    k_fold2<<<dim3(1024), 256, 0, stream>>>(w2, a1, w2s);
    k_conv2<<<dim3(8, 8, NB), 256, 0, stream>>>(h, w2s, kb, s2, q2);
    k_bn2fin<<<dim3(4), 256, 0, stream>>>(s2, q2, g2, b2, a2, b2f);
    k_softmax<<<dim3(1024, NB), 256, 0, stream>>>(kb, a2, b2f);
    k_final<<<dim3(8, 2, NB), 256, 0, stream>>>(kb, x, out);
}

// Round 5
// 715.340 us; speedup vs baseline: 1.1665x; 1.1264x over previous
//
#include <hip/hip_runtime.h>

typedef unsigned short u16;
typedef unsigned int u32;
typedef short bf16x8 __attribute__((ext_vector_type(8)));   // 8 bf16 (4 VGPRs)
typedef float f32x4 __attribute__((ext_vector_type(4)));

#define NB   64
#define NC   256
#define NO   256     // conv1 out channels
#define NM   1024    // LF*LF
#define PW   44      // padded width (32 + 2*6)
#define PPIX 1936    // 44*44

__device__ __forceinline__ u16 f2bf(float f) {
    u32 u = __builtin_bit_cast(u32, f);
    u32 r = (u + 0x7FFFu + ((u >> 16) & 1u)) >> 16;   // RNE
    return (u16)r;
}
// async global->LDS, 16B/lane; LDS dest is wave-uniform base + lane*16
__device__ __forceinline__ void ld16(const void* g, void* l) {
    __builtin_amdgcn_global_load_lds((const __attribute__((address_space(1))) u32*)g,
                                     (__attribute__((address_space(3))) u32*)l, 16, 0, 0);
}

#define VMCNT(n) { asm volatile("s_waitcnt vmcnt(" #n ")" ::: "memory"); __builtin_amdgcn_sched_barrier(0); }
#define LGKM(n)  { asm volatile("s_waitcnt lgkmcnt(" #n ")" ::: "memory"); __builtin_amdgcn_sched_barrier(0); }

// ---------- x[b][c][ij] (f32) -> xp[b][padded pix][c] (bf16), zero border (memset'd) ----------
__global__ __launch_bounds__(256) void k_transpose_pad(const float* __restrict__ x, u16* __restrict__ xp) {
    __shared__ u16 tile[64 * 65];
    const int b = blockIdx.z, ij0 = blockIdx.x * 64, c0 = blockIdx.y * 64;
    const int tid = threadIdx.x;
#pragma unroll
    for (int it = 0; it < 16; ++it) {
        int idx = it * 256 + tid;
        int cr = idx >> 6, ijr = idx & 63;
        tile[ijr * 65 + cr] = f2bf(x[((size_t)(b * NC + c0 + cr) << 10) + ij0 + ijr]);
    }
    __syncthreads();
#pragma unroll
    for (int it = 0; it < 16; ++it) {
        int idx = it * 256 + tid;
        int ijr = idx >> 6, cr = idx & 63;
        int pix = ij0 + ijr;
        int i = pix >> 5, j = pix & 31;
        int prow = (i + 6) * PW + (j + 6);
        xp[((size_t)(b * PPIX + prow) << 8) + c0 + cr] = tile[ijr * 65 + cr];
    }
}

// ---------- conv1_w (O,C,7,7) f32 -> w1t[tap][o][c] bf16 ----------
__global__ __launch_bounds__(256) void k_w1prep(const float* __restrict__ w1, u16* __restrict__ w1t) {
    const int o = blockIdx.x, c = threadIdx.x;
    const float* src = w1 + ((size_t)(o * NC + c)) * 49;
#pragma unroll
    for (int t = 0; t < 49; ++t)
        w1t[((size_t)(t * NO + o) << 8) + c] = f2bf(src[t]);
}

// ---------- conv1: 256x256 MFMA GEMM, register-prefetch pipeline ----------
// h[b][ij][o] = sum_{tap,c} xp[..][c] * w1t[tap][o][c]; + bn1 stats.
// K = 392 chunks of 32 (tap-inner for L2 locality; 4 ci x 49 taps x 2 kh).
// LDS 128 KiB: lsA/lsB = [4 regions][256 rows][32 u16]; region = chunk & 3.
// Per phase u (one chunk, 32 MFMA/wave):
//   vmcnt(4)          -> chunk u+1's staging (issued phase u-2) landed
//   s_barrier         -> visible to all waves
//   ds_read x12       -> chunk u+1 fragments into the OTHER reg set
//   glld x4           -> stage chunk u+3 into region (u+3)&3
//   lgkmcnt(12)       -> phase u-1's reads done (this phase's 12 in flight)
//   32 MFMA           -> pure-register, from reg set loaded last phase
// Reads have a full phase (~300 cyc) to land; loads keep a constant 8-deep
// queue; neither counter ever drains to 0 in the loop. Loop unrolled x2 so
// the fragment-buffer parity is a static register index (no scratch).
// Race-freedom: stage in phase u overwrites region (u-1)&3, whose last
// readers (RD(u-1), phase u-2) are drained by phase u-1's lgkmcnt(12),
// which precedes phase u's barrier in all waves' program order.
// Swizzle: physical 16B-chunk = logical ^ ((row>>1)&3), via pre-swizzled
// global source (glld dest linear) + same involution on ds_read addresses.
__global__ __launch_bounds__(512, 1) void k_conv1(const u16* __restrict__ xp, const u16* __restrict__ w1t,
                                                  u16* __restrict__ h, float* __restrict__ s1, float* __restrict__ q1) {
    __shared__ u16 lsA[4 * 256 * 32];   // 64 KB
    __shared__ u16 lsB[4 * 256 * 32];   // 64 KB
    const int tid = threadIdx.x, wv = tid >> 6, lane = tid & 63;
    const int wm = wv & 1, wn = wv >> 1;
    const int bb = blockIdx.z, ij0 = blockIdx.x * 256;

    f32x4 acc[8][4] = {};
    bf16x8 aX[8], bX[4], aY[8], bY[4];

    // ---- staging geometry: call c covers rows c*128 + (tid>>2), chunk tid&3 (16B)
    // pre-swizzled source chunk: lc = (tid&3) ^ ((tid>>3)&3)
    const int lc8 = (((tid & 3) ^ ((tid >> 3) & 3)) << 3);   // u16 elements
    int aRow[2], bRow[2], dstO[2];
#pragma unroll
    for (int c = 0; c < 2; ++c) {
        int r = (c << 7) + (tid >> 2);
        int pix = ij0 + r, i = pix >> 5, j = pix & 31;
        aRow[c] = ((bb * PPIX + i * PW + j) << 8) + lc8;
        bRow[c] = (r << 8) + lc8;
        dstO[c] = ((c << 7) + (wv << 4)) << 5;      // wave-uniform LDS u16 offset
    }
    // ---- fragment read bases: phys chunk = (lane>>4) ^ (((lane&15)>>1)&3)
    const int chsw = (((lane >> 4) ^ (((lane & 15) >> 1) & 3)) << 3);
    const u16* pA0 = lsA + (((wm << 7) + (lane & 15)) << 5) + chsw;
    const u16* pB0 = lsB + (((wn << 6) + (lane & 15)) << 5) + chsw;

    // ---- sequential chunk stage stream (one chunk = 32-K half-tile pair A+B)
    int sp = 0, sq = 0, stap = 0, sci = 0, skh = 0, sreg = 0;
    auto STAGE = [&]() {
        const int toff = (((sp << 1) * PW + (sq << 1)) << 8) + (sci << 6) + (skh << 5);
        const int woff = (stap << 16) + (sci << 6) + (skh << 5);
        u16* dA = (u16*)lsA + (sreg << 13);
        u16* dB = (u16*)lsB + (sreg << 13);
#pragma unroll
        for (int c = 0; c < 2; ++c) ld16(xp + aRow[c] + toff, dA + dstO[c]);
#pragma unroll
        for (int c = 0; c < 2; ++c) ld16(w1t + bRow[c] + woff, dB + dstO[c]);
        sreg = (sreg + 1) & 3;
        skh ^= 1;
        if (!skh) {
            ++stap; ++sq;
            if (sq == 7) { sq = 0; ++sp; }
            if (stap == 49) { stap = 0; sp = 0; sq = 0; ++sci; }
        }
    };
    auto RD = [&](int v, bf16x8 (&a)[8], bf16x8 (&b)[4]) {
        const int rb = (v & 3) << 13;
        const u16* pA = pA0 + rb;
        const u16* pB = pB0 + rb;
#pragma unroll
        for (int fi = 0; fi < 8; ++fi) a[fi] = *(const bf16x8*)(pA + (fi << 9));
#pragma unroll
        for (int fj = 0; fj < 4; ++fj) b[fj] = *(const bf16x8*)(pB + (fj << 9));
    };
    auto MM = [&](bf16x8 (&a)[8], bf16x8 (&b)[4]) {
        __builtin_amdgcn_s_setprio(1);
#pragma unroll
        for (int fi = 0; fi < 8; ++fi)
#pragma unroll
            for (int fj = 0; fj < 4; ++fj)
                acc[fi][fj] = __builtin_amdgcn_mfma_f32_16x16x32_bf16(a[fi], b[fj], acc[fi][fj], 0, 0, 0);
        __builtin_amdgcn_s_setprio(0);
    };

    // ---- prologue: stage chunks 0,1,2; read chunk 0 fragments
    STAGE(); STAGE(); STAGE();
    VMCNT(8);
    __builtin_amdgcn_s_barrier();
    RD(0, aX, bX);

    // ---- main loop: phases 0..387 (chunks 0..387), stages chunks 3..390
#pragma unroll 1
    for (int u = 0; u < 388; u += 2) {
        VMCNT(4);
        __builtin_amdgcn_s_barrier();
        RD(u + 1, aY, bY);
        STAGE();                         // chunk u+3
        LGKM(12);
        MM(aX, bX);                      // chunk u

        VMCNT(4);
        __builtin_amdgcn_s_barrier();
        RD(u + 2, aX, bX);
        STAGE();                         // chunk u+4
        LGKM(12);
        MM(aY, bY);                      // chunk u+1
    }
    // ---- tail: phases 388..391
    VMCNT(4);
    __builtin_amdgcn_s_barrier();
    RD(389, aY, bY);
    STAGE();                             // chunk 391
    LGKM(12);
    MM(aX, bX);                          // chunk 388

    VMCNT(4);
    __builtin_amdgcn_s_barrier();
    RD(390, aX, bX);
    LGKM(12);
    MM(aY, bY);                          // chunk 389

    VMCNT(0);
    __builtin_amdgcn_s_barrier();
    RD(391, aY, bY);
    LGKM(12);
    MM(aX, bX);                          // chunk 390

    LGKM(0);
    MM(aY, bY);                          // chunk 391

    // ---- epilogue: store bf16 h + per-column (o) sum/sumsq for bn1
    const int colb = (wn << 6) + (lane & 15);
    const int rowb = ij0 + (wm << 7) + ((lane >> 4) << 2);
#pragma unroll
    for (int fj = 0; fj < 4; ++fj) {
        const int col = colb + (fj << 4);
        float s = 0.f, qq = 0.f;
#pragma unroll
        for (int fi = 0; fi < 8; ++fi) {
            const int row = rowb + (fi << 4);
#pragma unroll
            for (int v = 0; v < 4; ++v) {
                float val = acc[fi][fj][v];
                h[((size_t)((bb << 10) + row + v) << 8) + col] = f2bf(val);
                s += val; qq += val * val;
            }
        }
        s += __shfl_xor(s, 16);  s += __shfl_xor(s, 32);
        qq += __shfl_xor(qq, 16); qq += __shfl_xor(qq, 32);
        if (lane < 16) { atomicAdd(&s1[col], s); atomicAdd(&q1[col], qq); }
    }
}

// ---------- bn1 finalize: only the multiplicative part survives (additive shifts cancel in bn2) ----------
__global__ void k_bn1fin(const float* __restrict__ s1, const float* __restrict__ q1,
                         const float* __restrict__ g1, float* __restrict__ a1) {
    const int o = threadIdx.x;
    float mean = s1[o] * (1.f / 65536.f);
    float var  = fmaxf(q1[o] * (1.f / 65536.f) - mean * mean, 0.f);
    a1[o] = g1[o] * rsqrtf(var + 1e-5f);
}

// ---------- fold bn1 scale into conv2 weights: w2s[m][c] = w2[m][c] * a1[c] (bf16) ----------
__global__ __launch_bounds__(256) void k_fold2(const float* __restrict__ w2, const float* __restrict__ a1,
                                               u16* __restrict__ w2s) {
    const int m = blockIdx.x, c = threadIdx.x;
    size_t idx = ((size_t)m << 8) + c;
    w2s[idx] = f2bf(w2[idx] * a1[c]);
}

// ---------- conv2 (1x1): kb[b][ij][m] = sum_c h[b][ij][c]*w2s[m][c]; + bn2 stats ----------
__global__ __launch_bounds__(256) void k_conv2(const u16* __restrict__ h, const u16* __restrict__ w2s,
                                               u16* __restrict__ kb, float* __restrict__ s2, float* __restrict__ q2) {
    __shared__ u16 lsA[128 * 32];
    __shared__ u16 lsB[128 * 32];
    const int tid = threadIdx.x, wv = tid >> 6, lane = tid & 63;
    const int wm = wv & 1, wn = wv >> 1;
    const int bb = blockIdx.z, ij0 = blockIdx.x * 128, m0 = blockIdx.y * 128;

    f32x4 acc[4][4] = {};
    const int lr = lane >> 2, lc8 = (lane & 3) << 3;
    int arow[2], brw[2];
    u16 *dA[2], *dB[2];
#pragma unroll
    for (int u = 0; u < 2; ++u) {
        int r = (wv << 5) + (u << 4) + lr;
        arow[u] = (((bb << 10) + ij0 + r) << 8) + lc8;
        brw[u]  = ((m0 + r) << 8) + lc8;
        dA[u] = lsA + (((wv << 5) + (u << 4)) << 5);
        dB[u] = lsB + (((wv << 5) + (u << 4)) << 5);
    }
    const u16* pA0 = lsA + (((wm << 6) + (lane & 15)) << 5) + ((lane >> 4) << 3);
    const u16* pB0 = lsB + (((wn << 6) + (lane & 15)) << 5) + ((lane >> 4) << 3);

    for (int s = 0; s < 8; ++s) {
        const int cc = s << 5;
#pragma unroll
        for (int u = 0; u < 2; ++u) {
            ld16(h + arow[u] + cc, dA[u]);
            ld16(w2s + brw[u] + cc, dB[u]);
        }
        __syncthreads();
        bf16x8 af[4], bv[4];
#pragma unroll
        for (int f = 0; f < 4; ++f) af[f] = *(const bf16x8*)(pA0 + (f << 9));
#pragma unroll
        for (int f = 0; f < 4; ++f) bv[f] = *(const bf16x8*)(pB0 + (f << 9));
#pragma unroll
        for (int fi = 0; fi < 4; ++fi)
#pragma unroll
            for (int fj = 0; fj < 4; ++fj)
                acc[fi][fj] = __builtin_amdgcn_mfma_f32_16x16x32_bf16(af[fi], bv[fj], acc[fi][fj], 0, 0, 0);
        __syncthreads();
    }
    const int colb = m0 + (wn << 6) + (lane & 15);
    const int rowb = ij0 + (wm << 6) + ((lane >> 4) << 2);
#pragma unroll
    for (int fj = 0; fj < 4; ++fj) {
        const int col = colb + (fj << 4);
        float s = 0.f, qq = 0.f;
#pragma unroll
        for (int fi = 0; fi < 4; ++fi) {
            const int row = rowb + (fi << 4);
#pragma unroll
            for (int v = 0; v < 4; ++v) {
                float val = acc[fi][fj][v];
                kb[((size_t)((bb << 10) + row + v) << 10) + col] = f2bf(val);
                s += val; qq += val * val;
            }
        }
        s += __shfl_xor(s, 16);  s += __shfl_xor(s, 32);
        qq += __shfl_xor(qq, 16); qq += __shfl_xor(qq, 32);
        if (lane < 16) { atomicAdd(&s2[col], s); atomicAdd(&q2[col], qq); }
    }
}

__global__ void k_bn2fin(const float* __restrict__ s2, const float* __restrict__ q2,
                         const float* __restrict__ g2, const float* __restrict__ b2,
                         float* __restrict__ a2, float* __restrict__ b2f) {
    const int m = blockIdx.x * 256 + threadIdx.x;
    float mean = s2[m] * (1.f / 65536.f);
    float var  = fmaxf(q2[m] * (1.f / 65536.f) - mean * mean, 0.f);
    float a = g2[m] * rsqrtf(var + 1e-5f);
    a2[m] = a;
    b2f[m] = b2[m] - mean * a;
}

// ---------- softmax over m (1024) per (b,ij) row, bn2 affine applied, in place ----------
__global__ __launch_bounds__(256) void k_softmax(u16* __restrict__ kb,
                                                 const float* __restrict__ a2, const float* __restrict__ b2f) {
    __shared__ float redm[4], reds[4];
    const int row = (blockIdx.y << 10) + blockIdx.x;
    u16* base = kb + ((size_t)row << 10);
    const int tid = threadIdx.x, lane = tid & 63, wv = tid >> 6;
    const int m0 = tid << 2;
    uint2 rw = *(const uint2*)(base + m0);
    float u[4];
    u[0] = __builtin_bit_cast(float, (rw.x & 0xFFFFu) << 16);
    u[1] = __builtin_bit_cast(float, rw.x & 0xFFFF0000u);
    u[2] = __builtin_bit_cast(float, (rw.y & 0xFFFFu) << 16);
    u[3] = __builtin_bit_cast(float, rw.y & 0xFFFF0000u);
#pragma unroll
    for (int i = 0; i < 4; ++i) u[i] = a2[m0 + i] * u[i] + b2f[m0 + i];
    float mx = fmaxf(fmaxf(u[0], u[1]), fmaxf(u[2], u[3]));
#pragma unroll
    for (int off = 32; off; off >>= 1) mx = fmaxf(mx, __shfl_xor(mx, off));
    if (lane == 0) redm[wv] = mx;
    __syncthreads();
    mx = fmaxf(fmaxf(redm[0], redm[1]), fmaxf(redm[2], redm[3]));
    float e[4], s = 0.f;
#pragma unroll
    for (int i = 0; i < 4; ++i) { e[i] = __expf(u[i] - mx); s += e[i]; }
#pragma unroll
    for (int off = 32; off; off >>= 1) s += __shfl_xor(s, off);
    if (lane == 0) reds[wv] = s;
    __syncthreads();
    float inv = 1.f / (reds[0] + reds[1] + reds[2] + reds[3]);
    u32 o0 = (u32)f2bf(e[0] * inv) | ((u32)f2bf(e[1] * inv) << 16);
    u32 o1 = (u32)f2bf(e[2] * inv) | ((u32)f2bf(e[3] * inv) << 16);
    *(uint2*)(base + m0) = make_uint2(o0, o1);
}

// ---------- final: out[b][ij][c] = sum_m ksm[b][ij][m] * x[b][c][m]; x is f32, out f32 ----------
__global__ __launch_bounds__(256) void k_final(const u16* __restrict__ ksm, const float* __restrict__ x,
                                               float* __restrict__ out) {
    __shared__ u16 lsA[128 * 32];
    __shared__ u16 lsB[128 * 32];
    const int tid = threadIdx.x, wv = tid >> 6, lane = tid & 63;
    const int wm = wv & 1, wn = wv >> 1;
    const int bb = blockIdx.z, ij0 = blockIdx.x * 128, c0 = blockIdx.y * 128;

    f32x4 acc[4][4] = {};
    const int lr = lane >> 2, lc8 = (lane & 3) << 3;
    int arow[2], brw[2];
    u16 *dA[2], *sB[2];
#pragma unroll
    for (int u = 0; u < 2; ++u) {
        int r = (wv << 5) + (u << 4) + lr;
        arow[u] = (((bb << 10) + ij0 + r) << 10) + lc8;
        brw[u]  = (((bb << 8) + c0 + r) << 10) + lc8;    // element offset into f32 x
        dA[u] = lsA + (((wv << 5) + (u << 4)) << 5);     // wave-uniform, glld
        sB[u] = lsB + (((wv << 5) + (u << 4) + lr) << 5) + lc8;  // per-lane store slot
    }
    const u16* pA0 = lsA + (((wm << 6) + (lane & 15)) << 5) + ((lane >> 4) << 3);
    const u16* pB0 = lsB + (((wn << 6) + (lane & 15)) << 5) + ((lane >> 4) << 3);

    for (int s = 0; s < 32; ++s) {
        const int cc = s << 5;
#pragma unroll
        for (int u = 0; u < 2; ++u) ld16(ksm + arow[u] + cc, dA[u]);
        float4 f00 = *(const float4*)(x + brw[0] + cc);
        float4 f01 = *(const float4*)(x + brw[0] + cc + 4);
        float4 f10 = *(const float4*)(x + brw[1] + cc);
        float4 f11 = *(const float4*)(x + brw[1] + cc + 4);
        uint4 vb0, vb1;
        vb0.x = (u32)f2bf(f00.x) | ((u32)f2bf(f00.y) << 16);
        vb0.y = (u32)f2bf(f00.z) | ((u32)f2bf(f00.w) << 16);
        vb0.z = (u32)f2bf(f01.x) | ((u32)f2bf(f01.y) << 16);
        vb0.w = (u32)f2bf(f01.z) | ((u32)f2bf(f01.w) << 16);
        vb1.x = (u32)f2bf(f10.x) | ((u32)f2bf(f10.y) << 16);
        vb1.y = (u32)f2bf(f10.z) | ((u32)f2bf(f10.w) << 16);
        vb1.z = (u32)f2bf(f11.x) | ((u32)f2bf(f11.y) << 16);
        vb1.w = (u32)f2bf(f11.z) | ((u32)f2bf(f11.w) << 16);
        *(uint4*)sB[0] = vb0;
        *(uint4*)sB[1] = vb1;
        __syncthreads();
        bf16x8 af[4], bv[4];
#pragma unroll
        for (int f = 0; f < 4; ++f) af[f] = *(const bf16x8*)(pA0 + (f << 9));
#pragma unroll
        for (int f = 0; f < 4; ++f) bv[f] = *(const bf16x8*)(pB0 + (f << 9));
#pragma unroll
        for (int fi = 0; fi < 4; ++fi)
#pragma unroll
            for (int fj = 0; fj < 4; ++fj)
                acc[fi][fj] = __builtin_amdgcn_mfma_f32_16x16x32_bf16(af[fi], bv[fj], acc[fi][fj], 0, 0, 0);
        __syncthreads();
    }
    const int colb = c0 + (wn << 6) + (lane & 15);
    const int rowb = ij0 + (wm << 6) + ((lane >> 4) << 2);
#pragma unroll
    for (int fi = 0; fi < 4; ++fi) {
        const int row = rowb + (fi << 4);
#pragma unroll
        for (int fj = 0; fj < 4; ++fj) {
            const int col = colb + (fj << 4);
#pragma unroll
            for (int v = 0; v < 4; ++v)
                out[((size_t)((bb << 10) + row + v) << 8) + col] = acc[fi][fj][v];
        }
    }
}

extern "C" void kernel_launch(void* const* d_in, const int* in_sizes, int n_in,
                              void* d_out, int out_size, void* d_ws, size_t ws_size,
                              hipStream_t stream) {
    const float* x  = (const float*)d_in[0];
    const float* w1 = (const float*)d_in[1];
    // d_in[2] = conv1_b : cancels through bn1
    const float* g1 = (const float*)d_in[3];
    // d_in[4] = bn1_b : cancels through bn2 (additive per-c constant -> per-m constant)
    const float* w2 = (const float*)d_in[5];
    // d_in[6] = conv2_b : cancels through bn2
    const float* g2 = (const float*)d_in[7];
    const float* b2 = (const float*)d_in[8];
    float* out = (float*)d_out;
    char* ws = (char*)d_ws;

    // ws layout (~174.3 MB): region0 shared by xp (63.4MB, dead after conv1) and kb (134MB)
    u16* xp  = (u16*)ws;
    u16* kb  = (u16*)ws;
    u16* h   = (u16*)(ws + 134217728);                 // 33.5 MB
    u16* w1t = (u16*)(ws + 134217728 + 33554432);      // 6.4 MB, shared with w2s (dead after conv1)
    u16* w2s = w1t;
    char* sm = ws + 134217728 + 33554432 + 6422528;
    float* s1  = (float*)(sm);
    float* q1  = (float*)(sm + 1024);
    float* s2  = (float*)(sm + 2048);
    float* q2  = (float*)(sm + 6144);
    float* a1  = (float*)(sm + 10240);
    float* a2  = (float*)(sm + 14336);
    float* b2f = (float*)(sm + 18432);

    hipMemsetAsync(sm, 0, 10240, stream);                             // stats accumulators
    hipMemsetAsync(xp, 0, (size_t)NB * PPIX * 256 * 2, stream);       // padded-input zeros
    k_transpose_pad<<<dim3(16, 4, NB), 256, 0, stream>>>(x, xp);
    k_w1prep<<<dim3(256), 256, 0, stream>>>(w1, w1t);
    k_conv1<<<dim3(4, 1, NB), 512, 0, stream>>>(xp, w1t, h, s1, q1);
    k_bn1fin<<<dim3(1), 256, 0, stream>>>(s1, q1, g1, a1);
    k_fold2<<<dim3(1024), 256, 0, stream>>>(w2, a1, w2s);
    k_conv2<<<dim3(8, 8, NB), 256, 0, stream>>>(h, w2s, kb, s2, q2);
    k_bn2fin<<<dim3(4), 256, 0, stream>>>(s2, q2, g2, b2, a2, b2f);
    k_softmax<<<dim3(1024, NB), 256, 0, stream>>>(kb, a2, b2f);
    k_final<<<dim3(8, 2, NB), 256, 0, stream>>>(kb, x, out);
}

// Round 6
// 673.698 us; speedup vs baseline: 1.2386x; 1.0618x over previous
//
#include <hip/hip_runtime.h>

typedef unsigned short u16;
typedef unsigned int u32;
typedef short bf16x8 __attribute__((ext_vector_type(8)));   // 8 bf16 (4 VGPRs)
typedef float f32x4 __attribute__((ext_vector_type(4)));

#define NB   64
#define NC   256
#define NO   256     // conv1 out channels
#define NM   1024    // LF*LF
#define PW   44      // padded width (32 + 2*6)
#define PPIX 1936    // 44*44

__device__ __forceinline__ u16 f2bf(float f) {
    u32 u = __builtin_bit_cast(u32, f);
    u32 r = (u + 0x7FFFu + ((u >> 16) & 1u)) >> 16;   // RNE
    return (u16)r;
}
__device__ __forceinline__ float bf2f(u32 lo16) {
    return __builtin_bit_cast(float, lo16 << 16);
}
// async global->LDS, 16B/lane; LDS dest is wave-uniform base + lane*16
__device__ __forceinline__ void ld16(const void* g, void* l) {
    __builtin_amdgcn_global_load_lds((const __attribute__((address_space(1))) u32*)g,
                                     (__attribute__((address_space(3))) u32*)l, 16, 0, 0);
}

#define VMCNT(n) { asm volatile("s_waitcnt vmcnt(" #n ")" ::: "memory"); __builtin_amdgcn_sched_barrier(0); }
#define LGKM(n)  { asm volatile("s_waitcnt lgkmcnt(" #n ")" ::: "memory"); __builtin_amdgcn_sched_barrier(0); }

// ---------- x[b][c][ij] (f32) -> xp[b][padded pix][c] (bf16), zero border (memset'd) ----------
__global__ __launch_bounds__(256) void k_transpose_pad(const float* __restrict__ x, u16* __restrict__ xp) {
    __shared__ u16 tile[64 * 65];
    const int b = blockIdx.z, ij0 = blockIdx.x * 64, c0 = blockIdx.y * 64;
    const int tid = threadIdx.x;
#pragma unroll
    for (int it = 0; it < 16; ++it) {
        int idx = it * 256 + tid;
        int cr = idx >> 6, ijr = idx & 63;
        tile[ijr * 65 + cr] = f2bf(x[((size_t)(b * NC + c0 + cr) << 10) + ij0 + ijr]);
    }
    __syncthreads();
#pragma unroll
    for (int it = 0; it < 16; ++it) {
        int idx = it * 256 + tid;
        int ijr = idx >> 6, cr = idx & 63;
        int pix = ij0 + ijr;
        int i = pix >> 5, j = pix & 31;
        int prow = (i + 6) * PW + (j + 6);
        xp[((size_t)(b * PPIX + prow) << 8) + c0 + cr] = tile[ijr * 65 + cr];
    }
}

// ---------- conv1_w (O,C,7,7) f32 -> w1t[tap][o][c] bf16 ----------
__global__ __launch_bounds__(256) void k_w1prep(const float* __restrict__ w1, u16* __restrict__ w1t) {
    const int o = blockIdx.x, c = threadIdx.x;
    const float* src = w1 + ((size_t)(o * NC + c)) * 49;
#pragma unroll
    for (int t = 0; t < 49; ++t)
        w1t[((size_t)(t * NO + o) << 8) + c] = f2bf(src[t]);
}

// ---------- conv1: 256x256 MFMA GEMM, register-prefetch pipeline (UNCHANGED, 355us/56% MfmaUtil) ----------
__global__ __launch_bounds__(512, 1) void k_conv1(const u16* __restrict__ xp, const u16* __restrict__ w1t,
                                                  u16* __restrict__ h, float* __restrict__ s1, float* __restrict__ q1) {
    __shared__ u16 lsA[4 * 256 * 32];   // 64 KB
    __shared__ u16 lsB[4 * 256 * 32];   // 64 KB
    const int tid = threadIdx.x, wv = tid >> 6, lane = tid & 63;
    const int wm = wv & 1, wn = wv >> 1;
    const int bb = blockIdx.z, ij0 = blockIdx.x * 256;

    f32x4 acc[8][4] = {};
    bf16x8 aX[8], bX[4], aY[8], bY[4];

    const int lc8 = (((tid & 3) ^ ((tid >> 3) & 3)) << 3);   // pre-swizzled source chunk
    int aRow[2], bRow[2], dstO[2];
#pragma unroll
    for (int c = 0; c < 2; ++c) {
        int r = (c << 7) + (tid >> 2);
        int pix = ij0 + r, i = pix >> 5, j = pix & 31;
        aRow[c] = ((bb * PPIX + i * PW + j) << 8) + lc8;
        bRow[c] = (r << 8) + lc8;
        dstO[c] = ((c << 7) + (wv << 4)) << 5;
    }
    const int chsw = (((lane >> 4) ^ (((lane & 15) >> 1) & 3)) << 3);
    const u16* pA0 = lsA + (((wm << 7) + (lane & 15)) << 5) + chsw;
    const u16* pB0 = lsB + (((wn << 6) + (lane & 15)) << 5) + chsw;

    int sp = 0, sq = 0, stap = 0, sci = 0, skh = 0, sreg = 0;
    auto STAGE = [&]() {
        const int toff = (((sp << 1) * PW + (sq << 1)) << 8) + (sci << 6) + (skh << 5);
        const int woff = (stap << 16) + (sci << 6) + (skh << 5);
        u16* dA = (u16*)lsA + (sreg << 13);
        u16* dB = (u16*)lsB + (sreg << 13);
#pragma unroll
        for (int c = 0; c < 2; ++c) ld16(xp + aRow[c] + toff, dA + dstO[c]);
#pragma unroll
        for (int c = 0; c < 2; ++c) ld16(w1t + bRow[c] + woff, dB + dstO[c]);
        sreg = (sreg + 1) & 3;
        skh ^= 1;
        if (!skh) {
            ++stap; ++sq;
            if (sq == 7) { sq = 0; ++sp; }
            if (stap == 49) { stap = 0; sp = 0; sq = 0; ++sci; }
        }
    };
    auto RD = [&](int v, bf16x8 (&a)[8], bf16x8 (&b)[4]) {
        const int rb = (v & 3) << 13;
        const u16* pA = pA0 + rb;
        const u16* pB = pB0 + rb;
#pragma unroll
        for (int fi = 0; fi < 8; ++fi) a[fi] = *(const bf16x8*)(pA + (fi << 9));
#pragma unroll
        for (int fj = 0; fj < 4; ++fj) b[fj] = *(const bf16x8*)(pB + (fj << 9));
    };
    auto MM = [&](bf16x8 (&a)[8], bf16x8 (&b)[4]) {
        __builtin_amdgcn_s_setprio(1);
#pragma unroll
        for (int fi = 0; fi < 8; ++fi)
#pragma unroll
            for (int fj = 0; fj < 4; ++fj)
                acc[fi][fj] = __builtin_amdgcn_mfma_f32_16x16x32_bf16(a[fi], b[fj], acc[fi][fj], 0, 0, 0);
        __builtin_amdgcn_s_setprio(0);
    };

    STAGE(); STAGE(); STAGE();
    VMCNT(8);
    __builtin_amdgcn_s_barrier();
    RD(0, aX, bX);

#pragma unroll 1
    for (int u = 0; u < 388; u += 2) {
        VMCNT(4);
        __builtin_amdgcn_s_barrier();
        RD(u + 1, aY, bY);
        STAGE();
        LGKM(12);
        MM(aX, bX);

        VMCNT(4);
        __builtin_amdgcn_s_barrier();
        RD(u + 2, aX, bX);
        STAGE();
        LGKM(12);
        MM(aY, bY);
    }
    VMCNT(4);
    __builtin_amdgcn_s_barrier();
    RD(389, aY, bY);
    STAGE();
    LGKM(12);
    MM(aX, bX);

    VMCNT(4);
    __builtin_amdgcn_s_barrier();
    RD(390, aX, bX);
    LGKM(12);
    MM(aY, bY);

    VMCNT(0);
    __builtin_amdgcn_s_barrier();
    RD(391, aY, bY);
    LGKM(12);
    MM(aX, bX);

    LGKM(0);
    MM(aY, bY);

    const int colb = (wn << 6) + (lane & 15);
    const int rowb = ij0 + (wm << 7) + ((lane >> 4) << 2);
#pragma unroll
    for (int fj = 0; fj < 4; ++fj) {
        const int col = colb + (fj << 4);
        float s = 0.f, qq = 0.f;
#pragma unroll
        for (int fi = 0; fi < 8; ++fi) {
            const int row = rowb + (fi << 4);
#pragma unroll
            for (int v = 0; v < 4; ++v) {
                float val = acc[fi][fj][v];
                h[((size_t)((bb << 10) + row + v) << 8) + col] = f2bf(val);
                s += val; qq += val * val;
            }
        }
        s += __shfl_xor(s, 16);  s += __shfl_xor(s, 32);
        qq += __shfl_xor(qq, 16); qq += __shfl_xor(qq, 32);
        if (lane < 16) { atomicAdd(&s1[col], s); atomicAdd(&q1[col], qq); }
    }
}

// ---------- bn1 finalize ----------
__global__ void k_bn1fin(const float* __restrict__ s1, const float* __restrict__ q1,
                         const float* __restrict__ g1, float* __restrict__ a1) {
    const int o = threadIdx.x;
    float mean = s1[o] * (1.f / 65536.f);
    float var  = fmaxf(q1[o] * (1.f / 65536.f) - mean * mean, 0.f);
    a1[o] = g1[o] * rsqrtf(var + 1e-5f);
}

// ---------- fold bn1 scale into conv2 weights ----------
__global__ __launch_bounds__(256) void k_fold2(const float* __restrict__ w2, const float* __restrict__ a1,
                                               u16* __restrict__ w2s) {
    const int m = blockIdx.x, c = threadIdx.x;
    size_t idx = ((size_t)m << 8) + c;
    w2s[idx] = f2bf(w2[idx] * a1[c]);
}

// ---------- conv2 (1x1): 256x256 tile, register-prefetch pipeline (port of conv1, NS=8) ----------
// kb[b][ij][m] = sum_c h[b][ij][c]*w2s[m][c]; + bn2 stats.
// grid 1024 linear: bid = r*64 + b  (b = bid&63 -> bid%8 = b%8 -> same-batch blocks
// colocate on one XCD for h/w2s L2 reuse). r = (ij_blk*4 + m_blk).
__global__ __launch_bounds__(512, 1) void k_conv2(const u16* __restrict__ h, const u16* __restrict__ w2s,
                                                  u16* __restrict__ kb, float* __restrict__ s2, float* __restrict__ q2) {
    __shared__ u16 lsA[4 * 256 * 32];
    __shared__ u16 lsB[4 * 256 * 32];
    const int tid = threadIdx.x, wv = tid >> 6, lane = tid & 63;
    const int wm = wv & 1, wn = wv >> 1;
    const int bid = blockIdx.x;
    const int bb = bid & 63, r2 = bid >> 6;
    const int ij0 = (r2 >> 2) << 8, m0 = (r2 & 3) << 8;

    f32x4 acc[8][4] = {};
    bf16x8 aX[8], bX[4], aY[8], bY[4];

    const int lc8 = (((tid & 3) ^ ((tid >> 3) & 3)) << 3);
    int aRow[2], bRow[2], dstO[2];
#pragma unroll
    for (int c = 0; c < 2; ++c) {
        int rr = (c << 7) + (tid >> 2);
        aRow[c] = (((bb << 10) + ij0 + rr) << 8) + lc8;
        bRow[c] = ((m0 + rr) << 8) + lc8;
        dstO[c] = ((c << 7) + (wv << 4)) << 5;
    }
    const int chsw = (((lane >> 4) ^ (((lane & 15) >> 1) & 3)) << 3);
    const u16* pA0 = lsA + (((wm << 7) + (lane & 15)) << 5) + chsw;
    const u16* pB0 = lsB + (((wn << 6) + (lane & 15)) << 5) + chsw;

    int sk = 0, sreg = 0;
    auto STAGE = [&]() {
        const int off = sk << 5;
        u16* dA = (u16*)lsA + (sreg << 13);
        u16* dB = (u16*)lsB + (sreg << 13);
#pragma unroll
        for (int c = 0; c < 2; ++c) ld16(h + aRow[c] + off, dA + dstO[c]);
#pragma unroll
        for (int c = 0; c < 2; ++c) ld16(w2s + bRow[c] + off, dB + dstO[c]);
        sreg = (sreg + 1) & 3;
        ++sk;
    };
    auto RD = [&](int v, bf16x8 (&a)[8], bf16x8 (&b)[4]) {
        const int rb = (v & 3) << 13;
        const u16* pA = pA0 + rb;
        const u16* pB = pB0 + rb;
#pragma unroll
        for (int fi = 0; fi < 8; ++fi) a[fi] = *(const bf16x8*)(pA + (fi << 9));
#pragma unroll
        for (int fj = 0; fj < 4; ++fj) b[fj] = *(const bf16x8*)(pB + (fj << 9));
    };
    auto MM = [&](bf16x8 (&a)[8], bf16x8 (&b)[4]) {
        __builtin_amdgcn_s_setprio(1);
#pragma unroll
        for (int fi = 0; fi < 8; ++fi)
#pragma unroll
            for (int fj = 0; fj < 4; ++fj)
                acc[fi][fj] = __builtin_amdgcn_mfma_f32_16x16x32_bf16(a[fi], b[fj], acc[fi][fj], 0, 0, 0);
        __builtin_amdgcn_s_setprio(0);
    };

    STAGE(); STAGE(); STAGE();
    VMCNT(8);
    __builtin_amdgcn_s_barrier();
    RD(0, aX, bX);

#pragma unroll 1
    for (int u = 0; u < 4; u += 2) {
        VMCNT(4);
        __builtin_amdgcn_s_barrier();
        RD(u + 1, aY, bY);
        STAGE();
        LGKM(12);
        MM(aX, bX);

        VMCNT(4);
        __builtin_amdgcn_s_barrier();
        RD(u + 2, aX, bX);
        STAGE();
        LGKM(12);
        MM(aY, bY);
    }
    VMCNT(4);
    __builtin_amdgcn_s_barrier();
    RD(5, aY, bY);
    STAGE();                             // chunk 7
    LGKM(12);
    MM(aX, bX);                          // chunk 4

    VMCNT(4);
    __builtin_amdgcn_s_barrier();
    RD(6, aX, bX);
    LGKM(12);
    MM(aY, bY);                          // chunk 5

    VMCNT(0);
    __builtin_amdgcn_s_barrier();
    RD(7, aY, bY);
    LGKM(12);
    MM(aX, bX);                          // chunk 6

    LGKM(0);
    MM(aY, bY);                          // chunk 7

    const int colb = m0 + (wn << 6) + (lane & 15);
    const int rowb = ij0 + (wm << 7) + ((lane >> 4) << 2);
#pragma unroll
    for (int fj = 0; fj < 4; ++fj) {
        const int col = colb + (fj << 4);
        float s = 0.f, qq = 0.f;
#pragma unroll
        for (int fi = 0; fi < 8; ++fi) {
            const int row = rowb + (fi << 4);
#pragma unroll
            for (int v = 0; v < 4; ++v) {
                float val = acc[fi][fj][v];
                kb[((size_t)((bb << 10) + row + v) << 10) + col] = f2bf(val);
                s += val; qq += val * val;
            }
        }
        s += __shfl_xor(s, 16);  s += __shfl_xor(s, 32);
        qq += __shfl_xor(qq, 16); qq += __shfl_xor(qq, 32);
        if (lane < 16) { atomicAdd(&s2[col], s); atomicAdd(&q2[col], qq); }
    }
}

__global__ void k_bn2fin(const float* __restrict__ s2, const float* __restrict__ q2,
                         const float* __restrict__ g2, const float* __restrict__ b2,
                         float* __restrict__ a2, float* __restrict__ b2f) {
    const int m = blockIdx.x * 256 + threadIdx.x;
    float mean = s2[m] * (1.f / 65536.f);
    float var  = fmaxf(q2[m] * (1.f / 65536.f) - mean * mean, 0.f);
    float a = g2[m] * rsqrtf(var + 1e-5f);
    a2[m] = a;
    b2f[m] = b2[m] - mean * a;
}

// ---------- rowstat: per-(b,ij) row, compute max(u) and 1/sum(exp(u-max)) with u = a2*kb+b2f ----------
// Replaces in-place softmax: no 134MB kb rewrite; k_final applies exp on the fly.
__global__ __launch_bounds__(256) void k_rowstat(const u16* __restrict__ kb,
                                                 const float* __restrict__ a2, const float* __restrict__ b2f,
                                                 float* __restrict__ rowmx, float* __restrict__ rowinv) {
    __shared__ float redm[4], reds[4];
    const int row = (blockIdx.y << 10) + blockIdx.x;
    const u16* base = kb + ((size_t)row << 10);
    const int tid = threadIdx.x, lane = tid & 63, wv = tid >> 6;
    const int m0 = tid << 2;
    uint2 rw = *(const uint2*)(base + m0);
    float u[4];
    u[0] = bf2f(rw.x & 0xFFFFu);
    u[1] = __builtin_bit_cast(float, rw.x & 0xFFFF0000u);
    u[2] = bf2f(rw.y & 0xFFFFu);
    u[3] = __builtin_bit_cast(float, rw.y & 0xFFFF0000u);
#pragma unroll
    for (int i = 0; i < 4; ++i) u[i] = a2[m0 + i] * u[i] + b2f[m0 + i];
    float mx = fmaxf(fmaxf(u[0], u[1]), fmaxf(u[2], u[3]));
#pragma unroll
    for (int off = 32; off; off >>= 1) mx = fmaxf(mx, __shfl_xor(mx, off));
    if (lane == 0) redm[wv] = mx;
    __syncthreads();
    mx = fmaxf(fmaxf(redm[0], redm[1]), fmaxf(redm[2], redm[3]));
    float s = 0.f;
#pragma unroll
    for (int i = 0; i < 4; ++i) s += __expf(u[i] - mx);
#pragma unroll
    for (int off = 32; off; off >>= 1) s += __shfl_xor(s, off);
    if (lane == 0) reds[wv] = s;
    __syncthreads();
    if (tid == 0) {
        rowmx[row] = mx;
        rowinv[row] = 1.f / (reds[0] + reds[1] + reds[2] + reds[3]);
    }
}

// ---------- final: out[b][ij][c] = sum_m softmax(kb)[b][ij][m] * x[b][c][m] ----------
// Full-c tile (128 ij x 256 c), 8 waves (2M x 4N), K=32 chunks of 32 m.
// A staged reg->transform(exp)->LDS (softmax fused via rowmx/rowinv); B = x f32->bf16.
// grid 512 linear: bid = ij_blk*64 + b -> same-batch blocks colocate on one XCD
// (x[b] fetched once per XCD). kb read exactly ONCE.
// LDS XOR chunk swizzle on both tiles: phys16B = logical ^ ((row>>1)&3).
__global__ __launch_bounds__(512, 2) void k_final(const u16* __restrict__ kb, const float* __restrict__ x,
                                                  const float* __restrict__ a2, const float* __restrict__ b2f,
                                                  const float* __restrict__ rowmx, const float* __restrict__ rowinv,
                                                  float* __restrict__ out) {
    __shared__ u16 lsA[128 * 32];   // 8 KB
    __shared__ u16 lsB[256 * 32];   // 16 KB
    const int tid = threadIdx.x, wv = tid >> 6, lane = tid & 63;
    const int wm = wv >> 2, wn = wv & 3;
    const int bid = blockIdx.x;
    const int bb = bid & 63, ij0 = (bid >> 6) << 7;

    f32x4 acc[4][4] = {};

    // A mapping: thread t -> row ar = t>>2 (0..127), m-offset am8 = (t&3)*8
    const int ar = tid >> 2, am8 = (tid & 3) << 3;
    const size_t aGlb = (((size_t)((bb << 10) + ij0 + ar)) << 10) + am8;
    u16* aLds = (u16*)lsA + (ar << 5) + (((tid & 3) ^ ((ar >> 1) & 3)) << 3);
    const float mxr = rowmx[(bb << 10) + ij0 + ar];
    const float invr = rowinv[(bb << 10) + ij0 + ar];
    // B mapping: thread t -> c-row br = t>>1 (0..255), m-offset bm16 = (t&1)*16
    const int br = tid >> 1, bm16 = (tid & 1) << 4;
    const size_t bGlb = (((size_t)((bb << 8) + br)) << 10) + bm16;
    const int bswz = (br >> 1) & 3;
    u16* bLds0 = (u16*)lsB + (br << 5) + (((((tid & 1) << 1) | 0) ^ bswz) << 3);
    u16* bLds1 = (u16*)lsB + (br << 5) + (((((tid & 1) << 1) | 1) ^ bswz) << 3);
    // fragment read bases
    const int chsw = (((lane >> 4) ^ (((lane & 15) >> 1) & 3)) << 3);
    const u16* pA0 = lsA + (((wm << 6) + (lane & 15)) << 5) + chsw;
    const u16* pB0 = lsB + (((wn << 6) + (lane & 15)) << 5) + chsw;

#pragma unroll 1
    for (int s = 0; s < 32; ++s) {
        const int cc = s << 5;
        // global loads (overlap previous MFMA; no LDS deps)
        uint4 av = *(const uint4*)(kb + aGlb + cc);
        float4 xb0 = *(const float4*)(x + bGlb + cc);
        float4 xb1 = *(const float4*)(x + bGlb + cc + 4);
        float4 xb2 = *(const float4*)(x + bGlb + cc + 8);
        float4 xb3 = *(const float4*)(x + bGlb + cc + 12);
        float4 a2lo = *(const float4*)(a2 + cc + am8);
        float4 a2hi = *(const float4*)(a2 + cc + am8 + 4);
        float4 bflo = *(const float4*)(b2f + cc + am8);
        float4 bfhi = *(const float4*)(b2f + cc + am8 + 4);
        // A transform: u = a2*v + b2f; p = exp(u - mx) * inv
        float va[8];
        va[0] = bf2f(av.x & 0xFFFFu); va[1] = __builtin_bit_cast(float, av.x & 0xFFFF0000u);
        va[2] = bf2f(av.y & 0xFFFFu); va[3] = __builtin_bit_cast(float, av.y & 0xFFFF0000u);
        va[4] = bf2f(av.z & 0xFFFFu); va[5] = __builtin_bit_cast(float, av.z & 0xFFFF0000u);
        va[6] = bf2f(av.w & 0xFFFFu); va[7] = __builtin_bit_cast(float, av.w & 0xFFFF0000u);
        float p[8];
        p[0] = __expf(a2lo.x * va[0] + bflo.x - mxr) * invr;
        p[1] = __expf(a2lo.y * va[1] + bflo.y - mxr) * invr;
        p[2] = __expf(a2lo.z * va[2] + bflo.z - mxr) * invr;
        p[3] = __expf(a2lo.w * va[3] + bflo.w - mxr) * invr;
        p[4] = __expf(a2hi.x * va[4] + bfhi.x - mxr) * invr;
        p[5] = __expf(a2hi.y * va[5] + bfhi.y - mxr) * invr;
        p[6] = __expf(a2hi.z * va[6] + bfhi.z - mxr) * invr;
        p[7] = __expf(a2hi.w * va[7] + bfhi.w - mxr) * invr;
        uint4 pa;
        pa.x = (u32)f2bf(p[0]) | ((u32)f2bf(p[1]) << 16);
        pa.y = (u32)f2bf(p[2]) | ((u32)f2bf(p[3]) << 16);
        pa.z = (u32)f2bf(p[4]) | ((u32)f2bf(p[5]) << 16);
        pa.w = (u32)f2bf(p[6]) | ((u32)f2bf(p[7]) << 16);
        uint4 pb0, pb1;
        pb0.x = (u32)f2bf(xb0.x) | ((u32)f2bf(xb0.y) << 16);
        pb0.y = (u32)f2bf(xb0.z) | ((u32)f2bf(xb0.w) << 16);
        pb0.z = (u32)f2bf(xb1.x) | ((u32)f2bf(xb1.y) << 16);
        pb0.w = (u32)f2bf(xb1.z) | ((u32)f2bf(xb1.w) << 16);
        pb1.x = (u32)f2bf(xb2.x) | ((u32)f2bf(xb2.y) << 16);
        pb1.y = (u32)f2bf(xb2.z) | ((u32)f2bf(xb2.w) << 16);
        pb1.z = (u32)f2bf(xb3.x) | ((u32)f2bf(xb3.y) << 16);
        pb1.w = (u32)f2bf(xb3.z) | ((u32)f2bf(xb3.w) << 16);
        __syncthreads();                // prev iteration's frag reads complete
        *(uint4*)aLds = pa;
        *(uint4*)bLds0 = pb0;
        *(uint4*)bLds1 = pb1;
        __syncthreads();                // stores visible
        bf16x8 af[4], bv[4];
#pragma unroll
        for (int f = 0; f < 4; ++f) af[f] = *(const bf16x8*)(pA0 + (f << 9));
#pragma unroll
        for (int f = 0; f < 4; ++f) bv[f] = *(const bf16x8*)(pB0 + (f << 9));
#pragma unroll
        for (int fi = 0; fi < 4; ++fi)
#pragma unroll
            for (int fj = 0; fj < 4; ++fj)
                acc[fi][fj] = __builtin_amdgcn_mfma_f32_16x16x32_bf16(af[fi], bv[fj], acc[fi][fj], 0, 0, 0);
    }
    const int colb = (wn << 6) + (lane & 15);
    const int rowb = ij0 + (wm << 6) + ((lane >> 4) << 2);
#pragma unroll
    for (int fi = 0; fi < 4; ++fi) {
        const int row = rowb + (fi << 4);
#pragma unroll
        for (int fj = 0; fj < 4; ++fj) {
            const int col = colb + (fj << 4);
#pragma unroll
            for (int v = 0; v < 4; ++v)
                out[((size_t)((bb << 10) + row + v) << 8) + col] = acc[fi][fj][v];
        }
    }
}

extern "C" void kernel_launch(void* const* d_in, const int* in_sizes, int n_in,
                              void* d_out, int out_size, void* d_ws, size_t ws_size,
                              hipStream_t stream) {
    const float* x  = (const float*)d_in[0];
    const float* w1 = (const float*)d_in[1];
    // d_in[2] = conv1_b : cancels through bn1
    const float* g1 = (const float*)d_in[3];
    // d_in[4] = bn1_b : cancels through bn2 (additive per-c constant -> per-m constant)
    const float* w2 = (const float*)d_in[5];
    // d_in[6] = conv2_b : cancels through bn2
    const float* g2 = (const float*)d_in[7];
    const float* b2 = (const float*)d_in[8];
    float* out = (float*)d_out;
    char* ws = (char*)d_ws;

    // ws layout (~174.3 MB): region0 shared by xp (63.4MB, dead after conv1) and kb (134MB)
    // h region (33.5MB) is dead after conv2 -> reused for rowmx/rowinv (512KB)
    u16* xp  = (u16*)ws;
    u16* kb  = (u16*)ws;
    u16* h   = (u16*)(ws + 134217728);                 // 33.5 MB
    float* rowmx  = (float*)(ws + 134217728);          // overlays dead h
    float* rowinv = rowmx + 65536;
    u16* w1t = (u16*)(ws + 134217728 + 33554432);      // 6.4 MB, shared with w2s (dead after conv1)
    u16* w2s = w1t;
    char* sm = ws + 134217728 + 33554432 + 6422528;
    float* s1  = (float*)(sm);
    float* q1  = (float*)(sm + 1024);
    float* s2  = (float*)(sm + 2048);
    float* q2  = (float*)(sm + 6144);
    float* a1  = (float*)(sm + 10240);
    float* a2  = (float*)(sm + 14336);
    float* b2f = (float*)(sm + 18432);

    hipMemsetAsync(sm, 0, 10240, stream);                             // stats accumulators
    hipMemsetAsync(xp, 0, (size_t)NB * PPIX * 256 * 2, stream);       // padded-input zeros
    k_transpose_pad<<<dim3(16, 4, NB), 256, 0, stream>>>(x, xp);
    k_w1prep<<<dim3(256), 256, 0, stream>>>(w1, w1t);
    k_conv1<<<dim3(4, 1, NB), 512, 0, stream>>>(xp, w1t, h, s1, q1);
    k_bn1fin<<<dim3(1), 256, 0, stream>>>(s1, q1, g1, a1);
    k_fold2<<<dim3(1024), 256, 0, stream>>>(w2, a1, w2s);
    k_conv2<<<dim3(1024), 512, 0, stream>>>(h, w2s, kb, s2, q2);
    k_bn2fin<<<dim3(4), 256, 0, stream>>>(s2, q2, g2, b2, a2, b2f);
    k_rowstat<<<dim3(1024, NB), 256, 0, stream>>>(kb, a2, b2f, rowmx, rowinv);
    k_final<<<dim3(512), 512, 0, stream>>>(kb, x, a2, b2f, rowmx, rowinv, out);
}

// Round 7
// 669.453 us; speedup vs baseline: 1.2465x; 1.0063x over previous
//
#include <hip/hip_runtime.h>

typedef unsigned short u16;
typedef unsigned int u32;
typedef short bf16x8 __attribute__((ext_vector_type(8)));   // 8 bf16 (4 VGPRs)
typedef float f32x4 __attribute__((ext_vector_type(4)));

#define NB   64
#define NC   256
#define NO   256     // conv1 out channels
#define NM   1024    // LF*LF
#define PW   44      // padded width (32 + 2*6)
#define PPIX 1936    // 44*44

__device__ __forceinline__ u16 f2bf(float f) {
    u32 u = __builtin_bit_cast(u32, f);
    u32 r = (u + 0x7FFFu + ((u >> 16) & 1u)) >> 16;   // RNE
    return (u16)r;
}
__device__ __forceinline__ float bf2f(u32 lo16) {
    return __builtin_bit_cast(float, lo16 << 16);
}
// async global->LDS, 16B/lane; LDS dest is wave-uniform base + lane*16
__device__ __forceinline__ void ld16(const void* g, void* l) {
    __builtin_amdgcn_global_load_lds((const __attribute__((address_space(1))) u32*)g,
                                     (__attribute__((address_space(3))) u32*)l, 16, 0, 0);
}

#define VMCNT(n) { asm volatile("s_waitcnt vmcnt(" #n ")" ::: "memory"); __builtin_amdgcn_sched_barrier(0); }
#define LGKM(n)  { asm volatile("s_waitcnt lgkmcnt(" #n ")" ::: "memory"); __builtin_amdgcn_sched_barrier(0); }

// ---------- x[b][c][ij] (f32) -> xp[b][padded pix][c] (bf16), zero border (memset'd) ----------
__global__ __launch_bounds__(256) void k_transpose_pad(const float* __restrict__ x, u16* __restrict__ xp) {
    __shared__ u16 tile[64 * 65];
    const int b = blockIdx.z, ij0 = blockIdx.x * 64, c0 = blockIdx.y * 64;
    const int tid = threadIdx.x;
#pragma unroll
    for (int it = 0; it < 16; ++it) {
        int idx = it * 256 + tid;
        int cr = idx >> 6, ijr = idx & 63;
        tile[ijr * 65 + cr] = f2bf(x[((size_t)(b * NC + c0 + cr) << 10) + ij0 + ijr]);
    }
    __syncthreads();
#pragma unroll
    for (int it = 0; it < 16; ++it) {
        int idx = it * 256 + tid;
        int ijr = idx >> 6, cr = idx & 63;
        int pix = ij0 + ijr;
        int i = pix >> 5, j = pix & 31;
        int prow = (i + 6) * PW + (j + 6);
        xp[((size_t)(b * PPIX + prow) << 8) + c0 + cr] = tile[ijr * 65 + cr];
    }
}

// ---------- conv1_w (O,C,7,7) f32 -> w1t[tap][o][c] bf16 ----------
__global__ __launch_bounds__(256) void k_w1prep(const float* __restrict__ w1, u16* __restrict__ w1t) {
    const int o = blockIdx.x, c = threadIdx.x;
    const float* src = w1 + ((size_t)(o * NC + c)) * 49;
#pragma unroll
    for (int t = 0; t < 49; ++t)
        w1t[((size_t)(t * NO + o) << 8) + c] = f2bf(src[t]);
}

// ---------- conv1: 256x256 MFMA GEMM, register-prefetch pipeline (UNCHANGED, ~340us/58% MfmaUtil) ----------
__global__ __launch_bounds__(512, 1) void k_conv1(const u16* __restrict__ xp, const u16* __restrict__ w1t,
                                                  u16* __restrict__ h, float* __restrict__ s1, float* __restrict__ q1) {
    __shared__ u16 lsA[4 * 256 * 32];   // 64 KB
    __shared__ u16 lsB[4 * 256 * 32];   // 64 KB
    const int tid = threadIdx.x, wv = tid >> 6, lane = tid & 63;
    const int wm = wv & 1, wn = wv >> 1;
    const int bb = blockIdx.z, ij0 = blockIdx.x * 256;

    f32x4 acc[8][4] = {};
    bf16x8 aX[8], bX[4], aY[8], bY[4];

    const int lc8 = (((tid & 3) ^ ((tid >> 3) & 3)) << 3);   // pre-swizzled source chunk
    int aRow[2], bRow[2], dstO[2];
#pragma unroll
    for (int c = 0; c < 2; ++c) {
        int r = (c << 7) + (tid >> 2);
        int pix = ij0 + r, i = pix >> 5, j = pix & 31;
        aRow[c] = ((bb * PPIX + i * PW + j) << 8) + lc8;
        bRow[c] = (r << 8) + lc8;
        dstO[c] = ((c << 7) + (wv << 4)) << 5;
    }
    const int chsw = (((lane >> 4) ^ (((lane & 15) >> 1) & 3)) << 3);
    const u16* pA0 = lsA + (((wm << 7) + (lane & 15)) << 5) + chsw;
    const u16* pB0 = lsB + (((wn << 6) + (lane & 15)) << 5) + chsw;

    int sp = 0, sq = 0, stap = 0, sci = 0, skh = 0, sreg = 0;
    auto STAGE = [&]() {
        const int toff = (((sp << 1) * PW + (sq << 1)) << 8) + (sci << 6) + (skh << 5);
        const int woff = (stap << 16) + (sci << 6) + (skh << 5);
        u16* dA = (u16*)lsA + (sreg << 13);
        u16* dB = (u16*)lsB + (sreg << 13);
#pragma unroll
        for (int c = 0; c < 2; ++c) ld16(xp + aRow[c] + toff, dA + dstO[c]);
#pragma unroll
        for (int c = 0; c < 2; ++c) ld16(w1t + bRow[c] + woff, dB + dstO[c]);
        sreg = (sreg + 1) & 3;
        skh ^= 1;
        if (!skh) {
            ++stap; ++sq;
            if (sq == 7) { sq = 0; ++sp; }
            if (stap == 49) { stap = 0; sp = 0; sq = 0; ++sci; }
        }
    };
    auto RD = [&](int v, bf16x8 (&a)[8], bf16x8 (&b)[4]) {
        const int rb = (v & 3) << 13;
        const u16* pA = pA0 + rb;
        const u16* pB = pB0 + rb;
#pragma unroll
        for (int fi = 0; fi < 8; ++fi) a[fi] = *(const bf16x8*)(pA + (fi << 9));
#pragma unroll
        for (int fj = 0; fj < 4; ++fj) b[fj] = *(const bf16x8*)(pB + (fj << 9));
    };
    auto MM = [&](bf16x8 (&a)[8], bf16x8 (&b)[4]) {
        __builtin_amdgcn_s_setprio(1);
#pragma unroll
        for (int fi = 0; fi < 8; ++fi)
#pragma unroll
            for (int fj = 0; fj < 4; ++fj)
                acc[fi][fj] = __builtin_amdgcn_mfma_f32_16x16x32_bf16(a[fi], b[fj], acc[fi][fj], 0, 0, 0);
        __builtin_amdgcn_s_setprio(0);
    };

    STAGE(); STAGE(); STAGE();
    VMCNT(8);
    __builtin_amdgcn_s_barrier();
    RD(0, aX, bX);

#pragma unroll 1
    for (int u = 0; u < 388; u += 2) {
        VMCNT(4);
        __builtin_amdgcn_s_barrier();
        RD(u + 1, aY, bY);
        STAGE();
        LGKM(12);
        MM(aX, bX);

        VMCNT(4);
        __builtin_amdgcn_s_barrier();
        RD(u + 2, aX, bX);
        STAGE();
        LGKM(12);
        MM(aY, bY);
    }
    VMCNT(4);
    __builtin_amdgcn_s_barrier();
    RD(389, aY, bY);
    STAGE();
    LGKM(12);
    MM(aX, bX);

    VMCNT(4);
    __builtin_amdgcn_s_barrier();
    RD(390, aX, bX);
    LGKM(12);
    MM(aY, bY);

    VMCNT(0);
    __builtin_amdgcn_s_barrier();
    RD(391, aY, bY);
    LGKM(12);
    MM(aX, bX);

    LGKM(0);
    MM(aY, bY);

    const int colb = (wn << 6) + (lane & 15);
    const int rowb = ij0 + (wm << 7) + ((lane >> 4) << 2);
#pragma unroll
    for (int fj = 0; fj < 4; ++fj) {
        const int col = colb + (fj << 4);
        float s = 0.f, qq = 0.f;
#pragma unroll
        for (int fi = 0; fi < 8; ++fi) {
            const int row = rowb + (fi << 4);
#pragma unroll
            for (int v = 0; v < 4; ++v) {
                float val = acc[fi][fj][v];
                h[((size_t)((bb << 10) + row + v) << 8) + col] = f2bf(val);
                s += val; qq += val * val;
            }
        }
        s += __shfl_xor(s, 16);  s += __shfl_xor(s, 32);
        qq += __shfl_xor(qq, 16); qq += __shfl_xor(qq, 32);
        if (lane < 16) { atomicAdd(&s1[col], s); atomicAdd(&q1[col], qq); }
    }
}

// ---------- fold2 (absorbs bn1fin): w2s[m][c] = w2[m][c] * g1[c]*rsqrt(var1[c]+eps) ----------
__global__ __launch_bounds__(256) void k_fold2(const float* __restrict__ w2,
                                               const float* __restrict__ s1, const float* __restrict__ q1,
                                               const float* __restrict__ g1, u16* __restrict__ w2s) {
    const int m = blockIdx.x, c = threadIdx.x;
    float mean = s1[c] * (1.f / 65536.f);
    float var  = fmaxf(q1[c] * (1.f / 65536.f) - mean * mean, 0.f);
    float a1   = g1[c] * rsqrtf(var + 1e-5f);
    size_t idx = ((size_t)m << 8) + c;
    w2s[idx] = f2bf(w2[idx] * a1);
}

// ---------- conv2 (1x1): 256x256 tile, register-prefetch pipeline (UNCHANGED) ----------
__global__ __launch_bounds__(512, 1) void k_conv2(const u16* __restrict__ h, const u16* __restrict__ w2s,
                                                  u16* __restrict__ kb, float* __restrict__ s2, float* __restrict__ q2) {
    __shared__ u16 lsA[4 * 256 * 32];
    __shared__ u16 lsB[4 * 256 * 32];
    const int tid = threadIdx.x, wv = tid >> 6, lane = tid & 63;
    const int wm = wv & 1, wn = wv >> 1;
    const int bid = blockIdx.x;
    const int bb = bid & 63, r2 = bid >> 6;
    const int ij0 = (r2 >> 2) << 8, m0 = (r2 & 3) << 8;

    f32x4 acc[8][4] = {};
    bf16x8 aX[8], bX[4], aY[8], bY[4];

    const int lc8 = (((tid & 3) ^ ((tid >> 3) & 3)) << 3);
    int aRow[2], bRow[2], dstO[2];
#pragma unroll
    for (int c = 0; c < 2; ++c) {
        int rr = (c << 7) + (tid >> 2);
        aRow[c] = (((bb << 10) + ij0 + rr) << 8) + lc8;
        bRow[c] = ((m0 + rr) << 8) + lc8;
        dstO[c] = ((c << 7) + (wv << 4)) << 5;
    }
    const int chsw = (((lane >> 4) ^ (((lane & 15) >> 1) & 3)) << 3);
    const u16* pA0 = lsA + (((wm << 7) + (lane & 15)) << 5) + chsw;
    const u16* pB0 = lsB + (((wn << 6) + (lane & 15)) << 5) + chsw;

    int sk = 0, sreg = 0;
    auto STAGE = [&]() {
        const int off = sk << 5;
        u16* dA = (u16*)lsA + (sreg << 13);
        u16* dB = (u16*)lsB + (sreg << 13);
#pragma unroll
        for (int c = 0; c < 2; ++c) ld16(h + aRow[c] + off, dA + dstO[c]);
#pragma unroll
        for (int c = 0; c < 2; ++c) ld16(w2s + bRow[c] + off, dB + dstO[c]);
        sreg = (sreg + 1) & 3;
        ++sk;
    };
    auto RD = [&](int v, bf16x8 (&a)[8], bf16x8 (&b)[4]) {
        const int rb = (v & 3) << 13;
        const u16* pA = pA0 + rb;
        const u16* pB = pB0 + rb;
#pragma unroll
        for (int fi = 0; fi < 8; ++fi) a[fi] = *(const bf16x8*)(pA + (fi << 9));
#pragma unroll
        for (int fj = 0; fj < 4; ++fj) b[fj] = *(const bf16x8*)(pB + (fj << 9));
    };
    auto MM = [&](bf16x8 (&a)[8], bf16x8 (&b)[4]) {
        __builtin_amdgcn_s_setprio(1);
#pragma unroll
        for (int fi = 0; fi < 8; ++fi)
#pragma unroll
            for (int fj = 0; fj < 4; ++fj)
                acc[fi][fj] = __builtin_amdgcn_mfma_f32_16x16x32_bf16(a[fi], b[fj], acc[fi][fj], 0, 0, 0);
        __builtin_amdgcn_s_setprio(0);
    };

    STAGE(); STAGE(); STAGE();
    VMCNT(8);
    __builtin_amdgcn_s_barrier();
    RD(0, aX, bX);

#pragma unroll 1
    for (int u = 0; u < 4; u += 2) {
        VMCNT(4);
        __builtin_amdgcn_s_barrier();
        RD(u + 1, aY, bY);
        STAGE();
        LGKM(12);
        MM(aX, bX);

        VMCNT(4);
        __builtin_amdgcn_s_barrier();
        RD(u + 2, aX, bX);
        STAGE();
        LGKM(12);
        MM(aY, bY);
    }
    VMCNT(4);
    __builtin_amdgcn_s_barrier();
    RD(5, aY, bY);
    STAGE();                             // chunk 7
    LGKM(12);
    MM(aX, bX);                          // chunk 4

    VMCNT(4);
    __builtin_amdgcn_s_barrier();
    RD(6, aX, bX);
    LGKM(12);
    MM(aY, bY);                          // chunk 5

    VMCNT(0);
    __builtin_amdgcn_s_barrier();
    RD(7, aY, bY);
    LGKM(12);
    MM(aX, bX);                          // chunk 6

    LGKM(0);
    MM(aY, bY);                          // chunk 7

    const int colb = m0 + (wn << 6) + (lane & 15);
    const int rowb = ij0 + (wm << 7) + ((lane >> 4) << 2);
#pragma unroll
    for (int fj = 0; fj < 4; ++fj) {
        const int col = colb + (fj << 4);
        float s = 0.f, qq = 0.f;
#pragma unroll
        for (int fi = 0; fi < 8; ++fi) {
            const int row = rowb + (fi << 4);
#pragma unroll
            for (int v = 0; v < 4; ++v) {
                float val = acc[fi][fj][v];
                kb[((size_t)((bb << 10) + row + v) << 10) + col] = f2bf(val);
                s += val; qq += val * val;
            }
        }
        s += __shfl_xor(s, 16);  s += __shfl_xor(s, 32);
        qq += __shfl_xor(qq, 16); qq += __shfl_xor(qq, 32);
        if (lane < 16) { atomicAdd(&s2[col], s); atomicAdd(&q2[col], qq); }
    }
}

__global__ void k_bn2fin(const float* __restrict__ s2, const float* __restrict__ q2,
                         const float* __restrict__ g2, const float* __restrict__ b2,
                         float* __restrict__ a2, float* __restrict__ b2f) {
    const int m = blockIdx.x * 256 + threadIdx.x;
    float mean = s2[m] * (1.f / 65536.f);
    float var  = fmaxf(q2[m] * (1.f / 65536.f) - mean * mean, 0.f);
    float a = g2[m] * rsqrtf(var + 1e-5f);
    a2[m] = a;
    b2f[m] = b2[m] - mean * a;
}

// ---------- rowstat v2: wave-per-row, 2048 blocks grid-stride (was 65536 tiny blocks = dispatch-bound) ----------
// per (b,ij) row: mx = max_m(a2*kb+b2f), inv = 1/sum(exp(u-mx)). Lane owns 16 fixed m.
__global__ __launch_bounds__(256) void k_rowstat(const u16* __restrict__ kb,
                                                 const float* __restrict__ a2, const float* __restrict__ b2f,
                                                 float* __restrict__ rowmx, float* __restrict__ rowinv) {
    const int tid = threadIdx.x, lane = tid & 63, wv = tid >> 6;
    const int m0 = lane << 4;                 // 16 m per lane
    float av[16], bv[16];
#pragma unroll
    for (int i = 0; i < 16; i += 4) {
        *(float4*)(av + i) = *(const float4*)(a2 + m0 + i);
        *(float4*)(bv + i) = *(const float4*)(b2f + m0 + i);
    }
    const int rbase = (blockIdx.x << 5) + (wv << 3);   // 32 rows/block, 8 per wave
#pragma unroll 1
    for (int r = 0; r < 8; ++r) {
        const int row = rbase + r;
        const u16* p = kb + ((size_t)row << 10) + m0;
        uint4 v0 = *(const uint4*)p;
        uint4 v1 = *(const uint4*)(p + 8);
        float u[16];
        u[0]  = bf2f(v0.x & 0xFFFFu); u[1]  = __builtin_bit_cast(float, v0.x & 0xFFFF0000u);
        u[2]  = bf2f(v0.y & 0xFFFFu); u[3]  = __builtin_bit_cast(float, v0.y & 0xFFFF0000u);
        u[4]  = bf2f(v0.z & 0xFFFFu); u[5]  = __builtin_bit_cast(float, v0.z & 0xFFFF0000u);
        u[6]  = bf2f(v0.w & 0xFFFFu); u[7]  = __builtin_bit_cast(float, v0.w & 0xFFFF0000u);
        u[8]  = bf2f(v1.x & 0xFFFFu); u[9]  = __builtin_bit_cast(float, v1.x & 0xFFFF0000u);
        u[10] = bf2f(v1.y & 0xFFFFu); u[11] = __builtin_bit_cast(float, v1.y & 0xFFFF0000u);
        u[12] = bf2f(v1.z & 0xFFFFu); u[13] = __builtin_bit_cast(float, v1.z & 0xFFFF0000u);
        u[14] = bf2f(v1.w & 0xFFFFu); u[15] = __builtin_bit_cast(float, v1.w & 0xFFFF0000u);
#pragma unroll
        for (int i = 0; i < 16; ++i) u[i] = av[i] * u[i] + bv[i];
        float mx = u[0];
#pragma unroll
        for (int i = 1; i < 16; ++i) mx = fmaxf(mx, u[i]);
#pragma unroll
        for (int off = 32; off; off >>= 1) mx = fmaxf(mx, __shfl_xor(mx, off));
        float s = 0.f;
#pragma unroll
        for (int i = 0; i < 16; ++i) s += __expf(u[i] - mx);
#pragma unroll
        for (int off = 32; off; off >>= 1) s += __shfl_xor(s, off);
        if (lane == 0) { rowmx[row] = mx; rowinv[row] = 1.f / s; }
    }
}

// ---------- final: out[b][ij][c] = sum_m softmax(kb)[b][ij][m] * x[b][c][m] (UNCHANGED) ----------
__global__ __launch_bounds__(512, 2) void k_final(const u16* __restrict__ kb, const float* __restrict__ x,
                                                  const float* __restrict__ a2, const float* __restrict__ b2f,
                                                  const float* __restrict__ rowmx, const float* __restrict__ rowinv,
                                                  float* __restrict__ out) {
    __shared__ u16 lsA[128 * 32];   // 8 KB
    __shared__ u16 lsB[256 * 32];   // 16 KB
    const int tid = threadIdx.x, wv = tid >> 6, lane = tid & 63;
    const int wm = wv >> 2, wn = wv & 3;
    const int bid = blockIdx.x;
    const int bb = bid & 63, ij0 = (bid >> 6) << 7;

    f32x4 acc[4][4] = {};

    const int ar = tid >> 2, am8 = (tid & 3) << 3;
    const size_t aGlb = (((size_t)((bb << 10) + ij0 + ar)) << 10) + am8;
    u16* aLds = (u16*)lsA + (ar << 5) + (((tid & 3) ^ ((ar >> 1) & 3)) << 3);
    const float mxr = rowmx[(bb << 10) + ij0 + ar];
    const float invr = rowinv[(bb << 10) + ij0 + ar];
    const int br = tid >> 1, bm16 = (tid & 1) << 4;
    const size_t bGlb = (((size_t)((bb << 8) + br)) << 10) + bm16;
    const int bswz = (br >> 1) & 3;
    u16* bLds0 = (u16*)lsB + (br << 5) + (((((tid & 1) << 1) | 0) ^ bswz) << 3);
    u16* bLds1 = (u16*)lsB + (br << 5) + (((((tid & 1) << 1) | 1) ^ bswz) << 3);
    const int chsw = (((lane >> 4) ^ (((lane & 15) >> 1) & 3)) << 3);
    const u16* pA0 = lsA + (((wm << 6) + (lane & 15)) << 5) + chsw;
    const u16* pB0 = lsB + (((wn << 6) + (lane & 15)) << 5) + chsw;

#pragma unroll 1
    for (int s = 0; s < 32; ++s) {
        const int cc = s << 5;
        uint4 av = *(const uint4*)(kb + aGlb + cc);
        float4 xb0 = *(const float4*)(x + bGlb + cc);
        float4 xb1 = *(const float4*)(x + bGlb + cc + 4);
        float4 xb2 = *(const float4*)(x + bGlb + cc + 8);
        float4 xb3 = *(const float4*)(x + bGlb + cc + 12);
        float4 a2lo = *(const float4*)(a2 + cc + am8);
        float4 a2hi = *(const float4*)(a2 + cc + am8 + 4);
        float4 bflo = *(const float4*)(b2f + cc + am8);
        float4 bfhi = *(const float4*)(b2f + cc + am8 + 4);
        float va[8];
        va[0] = bf2f(av.x & 0xFFFFu); va[1] = __builtin_bit_cast(float, av.x & 0xFFFF0000u);
        va[2] = bf2f(av.y & 0xFFFFu); va[3] = __builtin_bit_cast(float, av.y & 0xFFFF0000u);
        va[4] = bf2f(av.z & 0xFFFFu); va[5] = __builtin_bit_cast(float, av.z & 0xFFFF0000u);
        va[6] = bf2f(av.w & 0xFFFFu); va[7] = __builtin_bit_cast(float, av.w & 0xFFFF0000u);
        float p[8];
        p[0] = __expf(a2lo.x * va[0] + bflo.x - mxr) * invr;
        p[1] = __expf(a2lo.y * va[1] + bflo.y - mxr) * invr;
        p[2] = __expf(a2lo.z * va[2] + bflo.z - mxr) * invr;
        p[3] = __expf(a2lo.w * va[3] + bflo.w - mxr) * invr;
        p[4] = __expf(a2hi.x * va[4] + bfhi.x - mxr) * invr;
        p[5] = __expf(a2hi.y * va[5] + bfhi.y - mxr) * invr;
        p[6] = __expf(a2hi.z * va[6] + bfhi.z - mxr) * invr;
        p[7] = __expf(a2hi.w * va[7] + bfhi.w - mxr) * invr;
        uint4 pa;
        pa.x = (u32)f2bf(p[0]) | ((u32)f2bf(p[1]) << 16);
        pa.y = (u32)f2bf(p[2]) | ((u32)f2bf(p[3]) << 16);
        pa.z = (u32)f2bf(p[4]) | ((u32)f2bf(p[5]) << 16);
        pa.w = (u32)f2bf(p[6]) | ((u32)f2bf(p[7]) << 16);
        uint4 pb0, pb1;
        pb0.x = (u32)f2bf(xb0.x) | ((u32)f2bf(xb0.y) << 16);
        pb0.y = (u32)f2bf(xb0.z) | ((u32)f2bf(xb0.w) << 16);
        pb0.z = (u32)f2bf(xb1.x) | ((u32)f2bf(xb1.y) << 16);
        pb0.w = (u32)f2bf(xb1.z) | ((u32)f2bf(xb1.w) << 16);
        pb1.x = (u32)f2bf(xb2.x) | ((u32)f2bf(xb2.y) << 16);
        pb1.y = (u32)f2bf(xb2.z) | ((u32)f2bf(xb2.w) << 16);
        pb1.z = (u32)f2bf(xb3.x) | ((u32)f2bf(xb3.y) << 16);
        pb1.w = (u32)f2bf(xb3.z) | ((u32)f2bf(xb3.w) << 16);
        __syncthreads();
        *(uint4*)aLds = pa;
        *(uint4*)bLds0 = pb0;
        *(uint4*)bLds1 = pb1;
        __syncthreads();
        bf16x8 af[4], bv[4];
#pragma unroll
        for (int f = 0; f < 4; ++f) af[f] = *(const bf16x8*)(pA0 + (f << 9));
#pragma unroll
        for (int f = 0; f < 4; ++f) bv[f] = *(const bf16x8*)(pB0 + (f << 9));
#pragma unroll
        for (int fi = 0; fi < 4; ++fi)
#pragma unroll
            for (int fj = 0; fj < 4; ++fj)
                acc[fi][fj] = __builtin_amdgcn_mfma_f32_16x16x32_bf16(af[fi], bv[fj], acc[fi][fj], 0, 0, 0);
    }
    const int colb = (wn << 6) + (lane & 15);
    const int rowb = ij0 + (wm << 6) + ((lane >> 4) << 2);
#pragma unroll
    for (int fi = 0; fi < 4; ++fi) {
        const int row = rowb + (fi << 4);
#pragma unroll
        for (int fj = 0; fj < 4; ++fj) {
            const int col = colb + (fj << 4);
#pragma unroll
            for (int v = 0; v < 4; ++v)
                out[((size_t)((bb << 10) + row + v) << 8) + col] = acc[fi][fj][v];
        }
    }
}

extern "C" void kernel_launch(void* const* d_in, const int* in_sizes, int n_in,
                              void* d_out, int out_size, void* d_ws, size_t ws_size,
                              hipStream_t stream) {
    const float* x  = (const float*)d_in[0];
    const float* w1 = (const float*)d_in[1];
    // d_in[2] = conv1_b : cancels through bn1
    const float* g1 = (const float*)d_in[3];
    // d_in[4] = bn1_b : cancels through bn2 (additive per-c constant -> per-m constant)
    const float* w2 = (const float*)d_in[5];
    // d_in[6] = conv2_b : cancels through bn2
    const float* g2 = (const float*)d_in[7];
    const float* b2 = (const float*)d_in[8];
    float* out = (float*)d_out;
    char* ws = (char*)d_ws;

    // ws layout (~174.3 MB): region0 shared by xp (63.4MB, dead after conv1) and kb (134MB)
    // h region (33.5MB) is dead after conv2 -> reused for rowmx/rowinv (512KB)
    u16* xp  = (u16*)ws;
    u16* kb  = (u16*)ws;
    u16* h   = (u16*)(ws + 134217728);                 // 33.5 MB
    float* rowmx  = (float*)(ws + 134217728);          // overlays dead h
    float* rowinv = rowmx + 65536;
    u16* w1t = (u16*)(ws + 134217728 + 33554432);      // 6.4 MB, shared with w2s (dead after conv1)
    u16* w2s = w1t;
    char* sm = ws + 134217728 + 33554432 + 6422528;
    float* s1  = (float*)(sm);
    float* q1  = (float*)(sm + 1024);
    float* s2  = (float*)(sm + 2048);
    float* q2  = (float*)(sm + 6144);
    float* a2  = (float*)(sm + 14336);
    float* b2f = (float*)(sm + 18432);

    hipMemsetAsync(sm, 0, 10240, stream);                             // stats accumulators
    hipMemsetAsync(xp, 0, (size_t)NB * PPIX * 256 * 2, stream);       // padded-input zeros
    k_transpose_pad<<<dim3(16, 4, NB), 256, 0, stream>>>(x, xp);
    k_w1prep<<<dim3(256), 256, 0, stream>>>(w1, w1t);
    k_conv1<<<dim3(4, 1, NB), 512, 0, stream>>>(xp, w1t, h, s1, q1);
    k_fold2<<<dim3(1024), 256, 0, stream>>>(w2, s1, q1, g1, w2s);
    k_conv2<<<dim3(1024), 512, 0, stream>>>(h, w2s, kb, s2, q2);
    k_bn2fin<<<dim3(4), 256, 0, stream>>>(s2, q2, g2, b2, a2, b2f);
    k_rowstat<<<dim3(2048), 256, 0, stream>>>(kb, a2, b2f, rowmx, rowinv);
    k_final<<<dim3(512), 512, 0, stream>>>(kb, x, a2, b2f, rowmx, rowinv, out);
}

// Round 8
// 644.099 us; speedup vs baseline: 1.2955x; 1.0394x over previous
//
#include <hip/hip_runtime.h>

typedef unsigned short u16;
typedef unsigned int u32;
typedef short bf16x8 __attribute__((ext_vector_type(8)));   // 8 bf16 (4 VGPRs)
typedef float f32x4 __attribute__((ext_vector_type(4)));

#define NB   64
#define NC   256
#define NO   256     // conv1 out channels
#define NM   1024    // LF*LF
#define PW   44      // padded width (32 + 2*6)
#define PPIX 1936    // 44*44

__device__ __forceinline__ u16 f2bf(float f) {
    u32 u = __builtin_bit_cast(u32, f);
    u32 r = (u + 0x7FFFu + ((u >> 16) & 1u)) >> 16;   // RNE
    return (u16)r;
}
__device__ __forceinline__ float bf2f(u32 lo16) {
    return __builtin_bit_cast(float, lo16 << 16);
}
// async global->LDS, 16B/lane; LDS dest is wave-uniform base + lane*16
__device__ __forceinline__ void ld16(const void* g, void* l) {
    __builtin_amdgcn_global_load_lds((const __attribute__((address_space(1))) u32*)g,
                                     (__attribute__((address_space(3))) u32*)l, 16, 0, 0);
}

#define VMCNT(n) { asm volatile("s_waitcnt vmcnt(" #n ")" ::: "memory"); __builtin_amdgcn_sched_barrier(0); }
#define LGKM(n)  { asm volatile("s_waitcnt lgkmcnt(" #n ")" ::: "memory"); __builtin_amdgcn_sched_barrier(0); }

// ---------- x[b][c][ij] (f32) -> xp[b][padded pix][c] (bf16), zero border (memset'd) ----------
__global__ __launch_bounds__(256) void k_transpose_pad(const float* __restrict__ x, u16* __restrict__ xp) {
    __shared__ u16 tile[64 * 65];
    const int b = blockIdx.z, ij0 = blockIdx.x * 64, c0 = blockIdx.y * 64;
    const int tid = threadIdx.x;
#pragma unroll
    for (int it = 0; it < 16; ++it) {
        int idx = it * 256 + tid;
        int cr = idx >> 6, ijr = idx & 63;
        tile[ijr * 65 + cr] = f2bf(x[((size_t)(b * NC + c0 + cr) << 10) + ij0 + ijr]);
    }
    __syncthreads();
#pragma unroll
    for (int it = 0; it < 16; ++it) {
        int idx = it * 256 + tid;
        int ijr = idx >> 6, cr = idx & 63;
        int pix = ij0 + ijr;
        int i = pix >> 5, j = pix & 31;
        int prow = (i + 6) * PW + (j + 6);
        xp[((size_t)(b * PPIX + prow) << 8) + c0 + cr] = tile[ijr * 65 + cr];
    }
}

// ---------- conv1_w (O,C,7,7) f32 -> w1t[tap][o][c] bf16 ----------
__global__ __launch_bounds__(256) void k_w1prep(const float* __restrict__ w1, u16* __restrict__ w1t) {
    const int o = blockIdx.x, c = threadIdx.x;
    const float* src = w1 + ((size_t)(o * NC + c)) * 49;
#pragma unroll
    for (int t = 0; t < 49; ++t)
        w1t[((size_t)(t * NO + o) << 8) + c] = f2bf(src[t]);
}

// ---------- conv1: 256x256 MFMA GEMM, BK=64 double-buffer + reg-prefetch ----------
// v2 schedule: 196 iterations (one (ci,tap) pair of 32-ch chunks each), ONE
// vmcnt(0)+barrier per iteration (was 2 per iteration at BK=32 -> per-phase
// sync cost halved; vmcnt(0) is free since the waited loads are a full
// ~2500-cycle iteration old).
// LDS unchanged: [4 regions][256][32] x (A,B); buf p = regions {2p, 2p+1}.
// Per iter j (p=j&1): vmcnt(0); barrier; RD 24 frags (both chunks) into regs;
// STAGE buf p^1 (8 glld, next pair); lgkm(12) -> MM(chunk even) covers the
// other 12 reads -> lgkm(0) free -> MM(chunk odd).
// Race-freedom: STAGE overwrites buf p^1, whose readers (iter j-1's RDs) were
// drained by iter j-1's lgkm(0) before MM, which precedes iter j's barrier in
// every wave's program order. Cross-wave glld visibility: own vmcnt(0) +
// barrier. Last iter peels STAGE (counters would walk past xp).
// Swizzle: physical 16B-chunk = logical ^ ((row>>1)&3), via pre-swizzled
// global source (glld dest linear) + same involution on ds_read addresses.
__global__ __launch_bounds__(512, 1) void k_conv1(const u16* __restrict__ xp, const u16* __restrict__ w1t,
                                                  u16* __restrict__ h, float* __restrict__ s1, float* __restrict__ q1) {
    __shared__ u16 lsA[4 * 256 * 32];   // 64 KB
    __shared__ u16 lsB[4 * 256 * 32];   // 64 KB
    const int tid = threadIdx.x, wv = tid >> 6, lane = tid & 63;
    const int wm = wv & 1, wn = wv >> 1;
    const int bb = blockIdx.z, ij0 = blockIdx.x * 256;

    f32x4 acc[8][4] = {};
    bf16x8 aX[8], bX[4], aY[8], bY[4];

    const int lc8 = (((tid & 3) ^ ((tid >> 3) & 3)) << 3);   // pre-swizzled source chunk
    int aRow[2], bRow[2], dstO[2];
#pragma unroll
    for (int c = 0; c < 2; ++c) {
        int r = (c << 7) + (tid >> 2);
        int pix = ij0 + r, i = pix >> 5, j = pix & 31;
        aRow[c] = ((bb * PPIX + i * PW + j) << 8) + lc8;
        bRow[c] = (r << 8) + lc8;
        dstO[c] = ((c << 7) + (wv << 4)) << 5;
    }
    const int chsw = (((lane >> 4) ^ (((lane & 15) >> 1) & 3)) << 3);
    const u16* pA0 = lsA + (((wm << 7) + (lane & 15)) << 5) + chsw;
    const u16* pB0 = lsB + (((wn << 6) + (lane & 15)) << 5) + chsw;

    // stage stream: one call stages a FULL (ci,tap) pair (kh0+kh1) into buf sbuf
    int sp = 0, sq = 0, stap = 0, sci = 0, sbuf = 0;
    auto STAGE = [&]() {
        const int tbase = (((sp << 1) * PW + (sq << 1)) << 8) + (sci << 6);
        const int wbase = (stap << 16) + (sci << 6);
#pragma unroll
        for (int kh = 0; kh < 2; ++kh) {
            u16* dA = (u16*)lsA + (((sbuf << 1) | kh) << 13);
            u16* dB = (u16*)lsB + (((sbuf << 1) | kh) << 13);
            const int o = kh << 5;
#pragma unroll
            for (int c = 0; c < 2; ++c) ld16(xp + aRow[c] + tbase + o, dA + dstO[c]);
#pragma unroll
            for (int c = 0; c < 2; ++c) ld16(w1t + bRow[c] + wbase + o, dB + dstO[c]);
        }
        sbuf ^= 1;
        ++stap; ++sq;
        if (sq == 7) { sq = 0; ++sp; }
        if (stap == 49) { stap = 0; sp = 0; sq = 0; ++sci; }
    };
    auto RD = [&](int v, bf16x8 (&a)[8], bf16x8 (&b)[4]) {
        const int rb = v << 13;
        const u16* pA = pA0 + rb;
        const u16* pB = pB0 + rb;
#pragma unroll
        for (int fi = 0; fi < 8; ++fi) a[fi] = *(const bf16x8*)(pA + (fi << 9));
#pragma unroll
        for (int fj = 0; fj < 4; ++fj) b[fj] = *(const bf16x8*)(pB + (fj << 9));
    };
    auto MM = [&](bf16x8 (&a)[8], bf16x8 (&b)[4]) {
        __builtin_amdgcn_s_setprio(1);
#pragma unroll
        for (int fi = 0; fi < 8; ++fi)
#pragma unroll
            for (int fj = 0; fj < 4; ++fj)
                acc[fi][fj] = __builtin_amdgcn_mfma_f32_16x16x32_bf16(a[fi], b[fj], acc[fi][fj], 0, 0, 0);
        __builtin_amdgcn_s_setprio(0);
    };

    // prologue: stage pair 0 into buf 0
    STAGE();

#pragma unroll 1
    for (int j = 0; j < 196; ++j) {
        const int p = j & 1;
        VMCNT(0);                              // buf p's 8 loads landed (issued last iter)
        __builtin_amdgcn_s_barrier();          // visibility + WAR protection
        __builtin_amdgcn_sched_barrier(0);
        RD(p << 1, aX, bX);                    // chunk kh0: 12 ds_read
        RD((p << 1) | 1, aY, bY);              // chunk kh1: 12 ds_read
        if (j < 195) STAGE();                  // stage pair j+1 into buf p^1
        LGKM(12);                              // kh0's 12 reads done (kh1's in flight)
        MM(aX, bX);                            // covers kh1's reads
        LGKM(0);                               // ~free
        MM(aY, bY);
    }

    // ---- epilogue: store bf16 h + per-column (o) sum/sumsq for bn1
    const int colb = (wn << 6) + (lane & 15);
    const int rowb = ij0 + (wm << 7) + ((lane >> 4) << 2);
#pragma unroll
    for (int fj = 0; fj < 4; ++fj) {
        const int col = colb + (fj << 4);
        float s = 0.f, qq = 0.f;
#pragma unroll
        for (int fi = 0; fi < 8; ++fi) {
            const int row = rowb + (fi << 4);
#pragma unroll
            for (int v = 0; v < 4; ++v) {
                float val = acc[fi][fj][v];
                h[((size_t)((bb << 10) + row + v) << 8) + col] = f2bf(val);
                s += val; qq += val * val;
            }
        }
        s += __shfl_xor(s, 16);  s += __shfl_xor(s, 32);
        qq += __shfl_xor(qq, 16); qq += __shfl_xor(qq, 32);
        if (lane < 16) { atomicAdd(&s1[col], s); atomicAdd(&q1[col], qq); }
    }
}

// ---------- fold2 (absorbs bn1fin): w2s[m][c] = w2[m][c] * g1[c]*rsqrt(var1[c]+eps) ----------
__global__ __launch_bounds__(256) void k_fold2(const float* __restrict__ w2,
                                               const float* __restrict__ s1, const float* __restrict__ q1,
                                               const float* __restrict__ g1, u16* __restrict__ w2s) {
    const int m = blockIdx.x, c = threadIdx.x;
    float mean = s1[c] * (1.f / 65536.f);
    float var  = fmaxf(q1[c] * (1.f / 65536.f) - mean * mean, 0.f);
    float a1   = g1[c] * rsqrtf(var + 1e-5f);
    size_t idx = ((size_t)m << 8) + c;
    w2s[idx] = f2bf(w2[idx] * a1);
}

// ---------- conv2 (1x1): 256x256 tile, register-prefetch pipeline (UNCHANGED) ----------
__global__ __launch_bounds__(512, 1) void k_conv2(const u16* __restrict__ h, const u16* __restrict__ w2s,
                                                  u16* __restrict__ kb, float* __restrict__ s2, float* __restrict__ q2) {
    __shared__ u16 lsA[4 * 256 * 32];
    __shared__ u16 lsB[4 * 256 * 32];
    const int tid = threadIdx.x, wv = tid >> 6, lane = tid & 63;
    const int wm = wv & 1, wn = wv >> 1;
    const int bid = blockIdx.x;
    const int bb = bid & 63, r2 = bid >> 6;
    const int ij0 = (r2 >> 2) << 8, m0 = (r2 & 3) << 8;

    f32x4 acc[8][4] = {};
    bf16x8 aX[8], bX[4], aY[8], bY[4];

    const int lc8 = (((tid & 3) ^ ((tid >> 3) & 3)) << 3);
    int aRow[2], bRow[2], dstO[2];
#pragma unroll
    for (int c = 0; c < 2; ++c) {
        int rr = (c << 7) + (tid >> 2);
        aRow[c] = (((bb << 10) + ij0 + rr) << 8) + lc8;
        bRow[c] = ((m0 + rr) << 8) + lc8;
        dstO[c] = ((c << 7) + (wv << 4)) << 5;
    }
    const int chsw = (((lane >> 4) ^ (((lane & 15) >> 1) & 3)) << 3);
    const u16* pA0 = lsA + (((wm << 7) + (lane & 15)) << 5) + chsw;
    const u16* pB0 = lsB + (((wn << 6) + (lane & 15)) << 5) + chsw;

    int sk = 0, sreg = 0;
    auto STAGE = [&]() {
        const int off = sk << 5;
        u16* dA = (u16*)lsA + (sreg << 13);
        u16* dB = (u16*)lsB + (sreg << 13);
#pragma unroll
        for (int c = 0; c < 2; ++c) ld16(h + aRow[c] + off, dA + dstO[c]);
#pragma unroll
        for (int c = 0; c < 2; ++c) ld16(w2s + bRow[c] + off, dB + dstO[c]);
        sreg = (sreg + 1) & 3;
        ++sk;
    };
    auto RD = [&](int v, bf16x8 (&a)[8], bf16x8 (&b)[4]) {
        const int rb = (v & 3) << 13;
        const u16* pA = pA0 + rb;
        const u16* pB = pB0 + rb;
#pragma unroll
        for (int fi = 0; fi < 8; ++fi) a[fi] = *(const bf16x8*)(pA + (fi << 9));
#pragma unroll
        for (int fj = 0; fj < 4; ++fj) b[fj] = *(const bf16x8*)(pB + (fj << 9));
    };
    auto MM = [&](bf16x8 (&a)[8], bf16x8 (&b)[4]) {
        __builtin_amdgcn_s_setprio(1);
#pragma unroll
        for (int fi = 0; fi < 8; ++fi)
#pragma unroll
            for (int fj = 0; fj < 4; ++fj)
                acc[fi][fj] = __builtin_amdgcn_mfma_f32_16x16x32_bf16(a[fi], b[fj], acc[fi][fj], 0, 0, 0);
        __builtin_amdgcn_s_setprio(0);
    };

    STAGE(); STAGE(); STAGE();
    VMCNT(8);
    __builtin_amdgcn_s_barrier();
    RD(0, aX, bX);

#pragma unroll 1
    for (int u = 0; u < 4; u += 2) {
        VMCNT(4);
        __builtin_amdgcn_s_barrier();
        RD(u + 1, aY, bY);
        STAGE();
        LGKM(12);
        MM(aX, bX);

        VMCNT(4);
        __builtin_amdgcn_s_barrier();
        RD(u + 2, aX, bX);
        STAGE();
        LGKM(12);
        MM(aY, bY);
    }
    VMCNT(4);
    __builtin_amdgcn_s_barrier();
    RD(5, aY, bY);
    STAGE();                             // chunk 7
    LGKM(12);
    MM(aX, bX);                          // chunk 4

    VMCNT(4);
    __builtin_amdgcn_s_barrier();
    RD(6, aX, bX);
    LGKM(12);
    MM(aY, bY);                          // chunk 5

    VMCNT(0);
    __builtin_amdgcn_s_barrier();
    RD(7, aY, bY);
    LGKM(12);
    MM(aX, bX);                          // chunk 6

    LGKM(0);
    MM(aY, bY);                          // chunk 7

    const int colb = m0 + (wn << 6) + (lane & 15);
    const int rowb = ij0 + (wm << 7) + ((lane >> 4) << 2);
#pragma unroll
    for (int fj = 0; fj < 4; ++fj) {
        const int col = colb + (fj << 4);
        float s = 0.f, qq = 0.f;
#pragma unroll
        for (int fi = 0; fi < 8; ++fi) {
            const int row = rowb + (fi << 4);
#pragma unroll
            for (int v = 0; v < 4; ++v) {
                float val = acc[fi][fj][v];
                kb[((size_t)((bb << 10) + row + v) << 10) + col] = f2bf(val);
                s += val; qq += val * val;
            }
        }
        s += __shfl_xor(s, 16);  s += __shfl_xor(s, 32);
        qq += __shfl_xor(qq, 16); qq += __shfl_xor(qq, 32);
        if (lane < 16) { atomicAdd(&s2[col], s); atomicAdd(&q2[col], qq); }
    }
}

__global__ void k_bn2fin(const float* __restrict__ s2, const float* __restrict__ q2,
                         const float* __restrict__ g2, const float* __restrict__ b2,
                         float* __restrict__ a2, float* __restrict__ b2f) {
    const int m = blockIdx.x * 256 + threadIdx.x;
    float mean = s2[m] * (1.f / 65536.f);
    float var  = fmaxf(q2[m] * (1.f / 65536.f) - mean * mean, 0.f);
    float a = g2[m] * rsqrtf(var + 1e-5f);
    a2[m] = a;
    b2f[m] = b2[m] - mean * a;
}

// ---------- rowstat: wave-per-row, 2048 blocks (UNCHANGED) ----------
__global__ __launch_bounds__(256) void k_rowstat(const u16* __restrict__ kb,
                                                 const float* __restrict__ a2, const float* __restrict__ b2f,
                                                 float* __restrict__ rowmx, float* __restrict__ rowinv) {
    const int tid = threadIdx.x, lane = tid & 63, wv = tid >> 6;
    const int m0 = lane << 4;                 // 16 m per lane
    float av[16], bv[16];
#pragma unroll
    for (int i = 0; i < 16; i += 4) {
        *(float4*)(av + i) = *(const float4*)(a2 + m0 + i);
        *(float4*)(bv + i) = *(const float4*)(b2f + m0 + i);
    }
    const int rbase = (blockIdx.x << 5) + (wv << 3);   // 32 rows/block, 8 per wave
#pragma unroll 1
    for (int r = 0; r < 8; ++r) {
        const int row = rbase + r;
        const u16* p = kb + ((size_t)row << 10) + m0;
        uint4 v0 = *(const uint4*)p;
        uint4 v1 = *(const uint4*)(p + 8);
        float u[16];
        u[0]  = bf2f(v0.x & 0xFFFFu); u[1]  = __builtin_bit_cast(float, v0.x & 0xFFFF0000u);
        u[2]  = bf2f(v0.y & 0xFFFFu); u[3]  = __builtin_bit_cast(float, v0.y & 0xFFFF0000u);
        u[4]  = bf2f(v0.z & 0xFFFFu); u[5]  = __builtin_bit_cast(float, v0.z & 0xFFFF0000u);
        u[6]  = bf2f(v0.w & 0xFFFFu); u[7]  = __builtin_bit_cast(float, v0.w & 0xFFFF0000u);
        u[8]  = bf2f(v1.x & 0xFFFFu); u[9]  = __builtin_bit_cast(float, v1.x & 0xFFFF0000u);
        u[10] = bf2f(v1.y & 0xFFFFu); u[11] = __builtin_bit_cast(float, v1.y & 0xFFFF0000u);
        u[12] = bf2f(v1.z & 0xFFFFu); u[13] = __builtin_bit_cast(float, v1.z & 0xFFFF0000u);
        u[14] = bf2f(v1.w & 0xFFFFu); u[15] = __builtin_bit_cast(float, v1.w & 0xFFFF0000u);
#pragma unroll
        for (int i = 0; i < 16; ++i) u[i] = av[i] * u[i] + bv[i];
        float mx = u[0];
#pragma unroll
        for (int i = 1; i < 16; ++i) mx = fmaxf(mx, u[i]);
#pragma unroll
        for (int off = 32; off; off >>= 1) mx = fmaxf(mx, __shfl_xor(mx, off));
        float s = 0.f;
#pragma unroll
        for (int i = 0; i < 16; ++i) s += __expf(u[i] - mx);
#pragma unroll
        for (int off = 32; off; off >>= 1) s += __shfl_xor(s, off);
        if (lane == 0) { rowmx[row] = mx; rowinv[row] = 1.f / s; }
    }
}

// ---------- final: out[b][ij][c] = sum_m softmax(kb)[b][ij][m] * x[b][c][m] (UNCHANGED) ----------
__global__ __launch_bounds__(512, 2) void k_final(const u16* __restrict__ kb, const float* __restrict__ x,
                                                  const float* __restrict__ a2, const float* __restrict__ b2f,
                                                  const float* __restrict__ rowmx, const float* __restrict__ rowinv,
                                                  float* __restrict__ out) {
    __shared__ u16 lsA[128 * 32];   // 8 KB
    __shared__ u16 lsB[256 * 32];   // 16 KB
    const int tid = threadIdx.x, wv = tid >> 6, lane = tid & 63;
    const int wm = wv >> 2, wn = wv & 3;
    const int bid = blockIdx.x;
    const int bb = bid & 63, ij0 = (bid >> 6) << 7;

    f32x4 acc[4][4] = {};

    const int ar = tid >> 2, am8 = (tid & 3) << 3;
    const size_t aGlb = (((size_t)((bb << 10) + ij0 + ar)) << 10) + am8;
    u16* aLds = (u16*)lsA + (ar << 5) + (((tid & 3) ^ ((ar >> 1) & 3)) << 3);
    const float mxr = rowmx[(bb << 10) + ij0 + ar];
    const float invr = rowinv[(bb << 10) + ij0 + ar];
    const int br = tid >> 1, bm16 = (tid & 1) << 4;
    const size_t bGlb = (((size_t)((bb << 8) + br)) << 10) + bm16;
    const int bswz = (br >> 1) & 3;
    u16* bLds0 = (u16*)lsB + (br << 5) + (((((tid & 1) << 1) | 0) ^ bswz) << 3);
    u16* bLds1 = (u16*)lsB + (br << 5) + (((((tid & 1) << 1) | 1) ^ bswz) << 3);
    const int chsw = (((lane >> 4) ^ (((lane & 15) >> 1) & 3)) << 3);
    const u16* pA0 = lsA + (((wm << 6) + (lane & 15)) << 5) + chsw;
    const u16* pB0 = lsB + (((wn << 6) + (lane & 15)) << 5) + chsw;

#pragma unroll 1
    for (int s = 0; s < 32; ++s) {
        const int cc = s << 5;
        uint4 av = *(const uint4*)(kb + aGlb + cc);
        float4 xb0 = *(const float4*)(x + bGlb + cc);
        float4 xb1 = *(const float4*)(x + bGlb + cc + 4);
        float4 xb2 = *(const float4*)(x + bGlb + cc + 8);
        float4 xb3 = *(const float4*)(x + bGlb + cc + 12);
        float4 a2lo = *(const float4*)(a2 + cc + am8);
        float4 a2hi = *(const float4*)(a2 + cc + am8 + 4);
        float4 bflo = *(const float4*)(b2f + cc + am8);
        float4 bfhi = *(const float4*)(b2f + cc + am8 + 4);
        float va[8];
        va[0] = bf2f(av.x & 0xFFFFu); va[1] = __builtin_bit_cast(float, av.x & 0xFFFF0000u);
        va[2] = bf2f(av.y & 0xFFFFu); va[3] = __builtin_bit_cast(float, av.y & 0xFFFF0000u);
        va[4] = bf2f(av.z & 0xFFFFu); va[5] = __builtin_bit_cast(float, av.z & 0xFFFF0000u);
        va[6] = bf2f(av.w & 0xFFFFu); va[7] = __builtin_bit_cast(float, av.w & 0xFFFF0000u);
        float p[8];
        p[0] = __expf(a2lo.x * va[0] + bflo.x - mxr) * invr;
        p[1] = __expf(a2lo.y * va[1] + bflo.y - mxr) * invr;
        p[2] = __expf(a2lo.z * va[2] + bflo.z - mxr) * invr;
        p[3] = __expf(a2lo.w * va[3] + bflo.w - mxr) * invr;
        p[4] = __expf(a2hi.x * va[4] + bfhi.x - mxr) * invr;
        p[5] = __expf(a2hi.y * va[5] + bfhi.y - mxr) * invr;
        p[6] = __expf(a2hi.z * va[6] + bfhi.z - mxr) * invr;
        p[7] = __expf(a2hi.w * va[7] + bfhi.w - mxr) * invr;
        uint4 pa;
        pa.x = (u32)f2bf(p[0]) | ((u32)f2bf(p[1]) << 16);
        pa.y = (u32)f2bf(p[2]) | ((u32)f2bf(p[3]) << 16);
        pa.z = (u32)f2bf(p[4]) | ((u32)f2bf(p[5]) << 16);
        pa.w = (u32)f2bf(p[6]) | ((u32)f2bf(p[7]) << 16);
        uint4 pb0, pb1;
        pb0.x = (u32)f2bf(xb0.x) | ((u32)f2bf(xb0.y) << 16);
        pb0.y = (u32)f2bf(xb0.z) | ((u32)f2bf(xb0.w) << 16);
        pb0.z = (u32)f2bf(xb1.x) | ((u32)f2bf(xb1.y) << 16);
        pb0.w = (u32)f2bf(xb1.z) | ((u32)f2bf(xb1.w) << 16);
        pb1.x = (u32)f2bf(xb2.x) | ((u32)f2bf(xb2.y) << 16);
        pb1.y = (u32)f2bf(xb2.z) | ((u32)f2bf(xb2.w) << 16);
        pb1.z = (u32)f2bf(xb3.x) | ((u32)f2bf(xb3.y) << 16);
        pb1.w = (u32)f2bf(xb3.z) | ((u32)f2bf(xb3.w) << 16);
        __syncthreads();
        *(uint4*)aLds = pa;
        *(uint4*)bLds0 = pb0;
        *(uint4*)bLds1 = pb1;
        __syncthreads();
        bf16x8 af[4], bv[4];
#pragma unroll
        for (int f = 0; f < 4; ++f) af[f] = *(const bf16x8*)(pA0 + (f << 9));
#pragma unroll
        for (int f = 0; f < 4; ++f) bv[f] = *(const bf16x8*)(pB0 + (f << 9));
#pragma unroll
        for (int fi = 0; fi < 4; ++fi)
#pragma unroll
            for (int fj = 0; fj < 4; ++fj)
                acc[fi][fj] = __builtin_amdgcn_mfma_f32_16x16x32_bf16(af[fi], bv[fj], acc[fi][fj], 0, 0, 0);
    }
    const int colb = (wn << 6) + (lane & 15);
    const int rowb = ij0 + (wm << 6) + ((lane >> 4) << 2);
#pragma unroll
    for (int fi = 0; fi < 4; ++fi) {
        const int row = rowb + (fi << 4);
#pragma unroll
        for (int fj = 0; fj < 4; ++fj) {
            const int col = colb + (fj << 4);
#pragma unroll
            for (int v = 0; v < 4; ++v)
                out[((size_t)((bb << 10) + row + v) << 8) + col] = acc[fi][fj][v];
        }
    }
}

extern "C" void kernel_launch(void* const* d_in, const int* in_sizes, int n_in,
                              void* d_out, int out_size, void* d_ws, size_t ws_size,
                              hipStream_t stream) {
    const float* x  = (const float*)d_in[0];
    const float* w1 = (const float*)d_in[1];
    // d_in[2] = conv1_b : cancels through bn1
    const float* g1 = (const float*)d_in[3];
    // d_in[4] = bn1_b : cancels through bn2 (additive per-c constant -> per-m constant)
    const float* w2 = (const float*)d_in[5];
    // d_in[6] = conv2_b : cancels through bn2
    const float* g2 = (const float*)d_in[7];
    const float* b2 = (const float*)d_in[8];
    float* out = (float*)d_out;
    char* ws = (char*)d_ws;

    // ws layout (~174.3 MB): region0 shared by xp (63.4MB, dead after conv1) and kb (134MB)
    // h region (33.5MB) is dead after conv2 -> reused for rowmx/rowinv (512KB)
    u16* xp  = (u16*)ws;
    u16* kb  = (u16*)ws;
    u16* h   = (u16*)(ws + 134217728);                 // 33.5 MB
    float* rowmx  = (float*)(ws + 134217728);          // overlays dead h
    float* rowinv = rowmx + 65536;
    u16* w1t = (u16*)(ws + 134217728 + 33554432);      // 6.4 MB, shared with w2s (dead after conv1)
    u16* w2s = w1t;
    char* sm = ws + 134217728 + 33554432 + 6422528;
    float* s1  = (float*)(sm);
    float* q1  = (float*)(sm + 1024);
    float* s2  = (float*)(sm + 2048);
    float* q2  = (float*)(sm + 6144);
    float* a2  = (float*)(sm + 14336);
    float* b2f = (float*)(sm + 18432);

    hipMemsetAsync(sm, 0, 10240, stream);                             // stats accumulators
    hipMemsetAsync(xp, 0, (size_t)NB * PPIX * 256 * 2, stream);       // padded-input zeros
    k_transpose_pad<<<dim3(16, 4, NB), 256, 0, stream>>>(x, xp);
    k_w1prep<<<dim3(256), 256, 0, stream>>>(w1, w1t);
    k_conv1<<<dim3(4, 1, NB), 512, 0, stream>>>(xp, w1t, h, s1, q1);
    k_fold2<<<dim3(1024), 256, 0, stream>>>(w2, s1, q1, g1, w2s);
    k_conv2<<<dim3(1024), 512, 0, stream>>>(h, w2s, kb, s2, q2);
    k_bn2fin<<<dim3(4), 256, 0, stream>>>(s2, q2, g2, b2, a2, b2f);
    k_rowstat<<<dim3(2048), 256, 0, stream>>>(kb, a2, b2f, rowmx, rowinv);
    k_final<<<dim3(512), 512, 0, stream>>>(kb, x, a2, b2f, rowmx, rowinv, out);
}